// Round 1
// baseline (6487.454 us; speedup 1.0000x reference)
//
#include <hip/hip_runtime.h>
#include <hip/hip_bf16.h>
#include <math.h>

// Problem constants (match reference)
constexpr int BB   = 2048;   // graphs per batch
constexpr int DF_  = 94;     // atom feature dim
constexpr int HH   = 376;    // hidden dim = 4*DF
constexpr int LL   = 64;     // max nodes per graph
constexpr int FIN  = 256;    // final dim
constexpr float PADV = -999.0f;

constexpr int TS = 64;       // GEMM tile M/N
constexpr int KS = 16;       // GEMM tile K

static inline int cdiv(int a, int b) { return (a + b - 1) / b; }

// ---------------------------------------------------------------------------
// small kernels
// ---------------------------------------------------------------------------

__global__ __launch_bounds__(256)
void init_deg_kernel(float* deg, int N) {
    int i = blockIdx.x * 256 + threadIdx.x;
    if (i < N) deg[i] = 1.0f;   // +1 self loop
}

__global__ __launch_bounds__(256)
void count_deg_kernel(const int* __restrict__ col, float* deg, int E) {
    int e = blockIdx.x * 256 + threadIdx.x;
    if (e < E) atomicAdd(&deg[col[e]], 1.0f);
}

__global__ __launch_bounds__(256)
void finalize_dinv_kernel(float* deg, int N) {
    int i = blockIdx.x * 256 + threadIdx.x;
    if (i < N) deg[i] = rsqrtf(deg[i]);
}

// single block: prefix-sum graph offsets, zero kl accumulator
__global__ void scan_kernel(const int* __restrict__ nn, int* goff, double* kl_acc) {
    if (threadIdx.x == 0) {
        int s = 0;
        for (int b = 0; b < BB; ++b) { goff[b] = s; s += nn[b]; }
        goff[BB] = s;
        *kl_acc = 0.0;
    }
}

// out[n,f] = dinv[n]^2 * hw[n,f] + bias[f]   (self-loop + bias term)
__global__ __launch_bounds__(256)
void combine_init_kernel(const float* __restrict__ hw, const float* __restrict__ dinv,
                         const float* __restrict__ bias, float* __restrict__ out,
                         int N, int F) {
    size_t idx = (size_t)blockIdx.x * 256 + threadIdx.x;
    if (idx >= (size_t)N * F) return;
    int n = (int)(idx / F), f = (int)(idx % F);
    float di = dinv[n];
    out[idx] = di * di * hw[idx] + bias[f];
}

// out[col[e], f] += dinv[row]*dinv[col] * hw[row, f]
__global__ __launch_bounds__(256)
void scatter_kernel(const int* __restrict__ row, const int* __restrict__ col,
                    const float* __restrict__ dinv, const float* __restrict__ hw,
                    float* __restrict__ out, int E, int F) {
    size_t idx = (size_t)blockIdx.x * 256 + threadIdx.x;
    if (idx >= (size_t)E * F) return;
    int e = (int)(idx / F), f = (int)(idx % F);
    int r = row[e], d = col[e];
    atomicAdd(&out[(size_t)d * F + f], dinv[r] * dinv[d] * hw[(size_t)r * F + f]);
}

__global__ __launch_bounds__(256)
void relu_kernel(float* __restrict__ x, size_t total) {
    size_t idx = (size_t)blockIdx.x * 256 + threadIdx.x;
    if (idx < total) x[idx] = fmaxf(x[idx], 0.0f);
}

// out[idx] = bias[idx % F]
__global__ __launch_bounds__(256)
void init_bias_kernel(float* __restrict__ out, const float* __restrict__ bias,
                      size_t total, int F) {
    size_t idx = (size_t)blockIdx.x * 256 + threadIdx.x;
    if (idx < total) out[idx] = bias[idx % F];
}

// ---------------------------------------------------------------------------
// tiled fp32 GEMM: C[M,Nn] = epilogue(A[M,K] @ W[K,Nn] + bias)
// rowvec != null: A_eff[m,k] = A[m,k] + rowvec[k]
// ATOMIC: atomicAdd partials into C (split-K path, no bias/epilogue)
// ---------------------------------------------------------------------------
template<bool RELU, bool NEGABS, bool ATOMIC>
__global__ __launch_bounds__(256)
void gemm_kernel(const float* __restrict__ A, const float* __restrict__ W,
                 const float* __restrict__ bias, const float* __restrict__ rowvec,
                 float* __restrict__ C, int M, int K, int Nn, int Kchunk) {
    __shared__ float As[KS][TS + 4];   // stride 68: 2-way max on write
    __shared__ float Ws[KS][TS + 2];   // stride 66

    int bm = blockIdx.x * TS;
    int bn = blockIdx.y * TS;
    int k0 = blockIdx.z * Kchunk;
    int k1 = min(K, k0 + Kchunk);

    int t  = threadIdx.x;
    int tx = t & 15, ty = t >> 4;

    float acc[4][4] = {};

    for (int kk0 = k0; kk0 < k1; kk0 += KS) {
        // A tile: 64 rows x 16 k
        int r = t >> 4, c = t & 15;
        #pragma unroll
        for (int i = 0; i < 4; ++i) {
            int m = bm + r + i * 16;
            int k = kk0 + c;
            float v = 0.0f;
            if (m < M && k < k1) {
                v = A[(size_t)m * K + k];
                if (rowvec) v += rowvec[k];
            }
            As[c][r + i * 16] = v;
        }
        // W tile: 16 k x 64 cols
        int wk = t >> 6, wn = t & 63;
        #pragma unroll
        for (int i = 0; i < 4; ++i) {
            int k = kk0 + wk + i * 4;
            int n = bn + wn;
            Ws[wk + i * 4][wn] = (k < k1 && n < Nn) ? W[(size_t)k * Nn + n] : 0.0f;
        }
        __syncthreads();

        #pragma unroll
        for (int kk = 0; kk < KS; ++kk) {
            float a[4], b[4];
            #pragma unroll
            for (int i = 0; i < 4; ++i) a[i] = As[kk][ty * 4 + i];
            #pragma unroll
            for (int j = 0; j < 4; ++j) b[j] = Ws[kk][tx * 4 + j];
            #pragma unroll
            for (int i = 0; i < 4; ++i)
                #pragma unroll
                for (int j = 0; j < 4; ++j)
                    acc[i][j] = fmaf(a[i], b[j], acc[i][j]);
        }
        __syncthreads();
    }

    #pragma unroll
    for (int i = 0; i < 4; ++i) {
        int m = bm + ty * 4 + i;
        if (m >= M) continue;
        #pragma unroll
        for (int j = 0; j < 4; ++j) {
            int n = bn + tx * 4 + j;
            if (n >= Nn) continue;
            float v = acc[i][j];
            if (ATOMIC) {
                atomicAdd(&C[(size_t)m * Nn + n], v);
            } else {
                if (bias) v += bias[n];
                if (RELU) v = fmaxf(v, 0.0f);
                if (NEGABS) v = -fabsf(v);
                C[(size_t)m * Nn + n] = v;
            }
        }
    }
}

static void gemm(hipStream_t s, const float* A, const float* W, const float* bias,
                 const float* rowvec, float* C, int M, int K, int Nn,
                 int mode /*0 plain,1 relu,2 negabs,3 atomic*/, int splitk) {
    dim3 grid(cdiv(M, TS), cdiv(Nn, TS), splitk);
    int Kchunk = (cdiv(K, splitk) + KS - 1) / KS * KS;
    switch (mode) {
        case 0: gemm_kernel<false, false, false><<<grid, 256, 0, s>>>(A, W, bias, rowvec, C, M, K, Nn, Kchunk); break;
        case 1: gemm_kernel<true,  false, false><<<grid, 256, 0, s>>>(A, W, bias, rowvec, C, M, K, Nn, Kchunk); break;
        case 2: gemm_kernel<false, true,  false><<<grid, 256, 0, s>>>(A, W, bias, rowvec, C, M, K, Nn, Kchunk); break;
        default: gemm_kernel<false, false, true><<<grid, 256, 0, s>>>(A, W, bias, rowvec, C, M, K, Nn, Kchunk); break;
    }
}

// ---------------------------------------------------------------------------
// pad-row mu/zlv (all pad rows identical) + exact pad kl contribution
// ---------------------------------------------------------------------------
__global__ __launch_bounds__(384)
void pad_vec_kernel(const float* __restrict__ seg,
                    const float* __restrict__ mW1, const float* __restrict__ mb1,
                    const float* __restrict__ mW2, const float* __restrict__ mb2,
                    const float* __restrict__ vW1, const float* __restrict__ vb1,
                    const float* __restrict__ vW2, const float* __restrict__ vb2,
                    float* __restrict__ mu_pad, float* __restrict__ zlv_pad,
                    double* kl_acc, int n_pad_rows) {
    __shared__ float t1[HH], t2[HH], red[HH];
    int j = threadIdx.x;
    if (j < HH) {
        float s1 = mb1[j], s2 = vb1[j];
        for (int k = 0; k < HH; ++k) {
            float p = PADV + seg[k];
            s1 += p * mW1[k * HH + j];
            s2 += p * vW1[k * HH + j];
        }
        t1[j] = fmaxf(s1, 0.0f);
        t2[j] = fmaxf(s2, 0.0f);
    }
    __syncthreads();
    if (j < HH) {
        float m = mb2[j], v = vb2[j];
        for (int k = 0; k < HH; ++k) {
            m += t1[k] * mW2[k * HH + j];
            v += t2[k] * vW2[k * HH + j];
        }
        float z = -fabsf(v);
        mu_pad[j]  = m;
        zlv_pad[j] = z;
        red[j] = 1.0f + z - m * m - expf(z);
    }
    __syncthreads();
    if (j == 0) {
        double s = 0.0;
        for (int k = 0; k < HH; ++k) s += (double)red[k];
        atomicAdd(kl_acc, s * (double)n_pad_rows);
    }
}

// d_seq[l,b,:] = (l < nn[b] ? h3[goff[b]+l,:] : PAD) + seg
__global__ __launch_bounds__(256)
void dseq_kernel(const float* __restrict__ h3, const float* __restrict__ seg,
                 const int* __restrict__ nn, const int* __restrict__ goff,
                 float* __restrict__ out, size_t total) {
    size_t idx = (size_t)blockIdx.x * 256 + threadIdx.x;
    if (idx >= total) return;
    int k = (int)(idx % HH);
    size_t rowi = idx / HH;
    int b = (int)(rowi % BB);
    int l = (int)(rowi / BB);
    float v = (l < nn[b]) ? h3[(size_t)(goff[b] + l) * HH + k] : PADV;
    out[idx] = v + seg[k];
}

__global__ __launch_bounds__(256)
void mask_kernel(const int* __restrict__ nn, float* __restrict__ out) {
    int idx = blockIdx.x * 256 + threadIdx.x;
    if (idx >= BB * LL) return;
    int b = idx / LL, l = idx % LL;
    out[idx] = (l >= nn[b]) ? 1.0f : 0.0f;
}

// amvo = mu + exp(zlv/2)*eps + con_emb[b,:] + affinity[b]
__global__ __launch_bounds__(256)
void amvo_kernel(const float* __restrict__ mu, const float* __restrict__ zlv,
                 const float* __restrict__ mu_pad, const float* __restrict__ zlv_pad,
                 const float* __restrict__ con_emb, const float* __restrict__ aff,
                 const float* __restrict__ eps,
                 const int* __restrict__ nn, const int* __restrict__ goff,
                 float* __restrict__ out, size_t total) {
    size_t idx = (size_t)blockIdx.x * 256 + threadIdx.x;
    if (idx >= total) return;
    int k = (int)(idx % HH);
    size_t rowi = idx / HH;
    int b = (int)(rowi % BB);
    int l = (int)(rowi / BB);
    float m, z;
    if (l < nn[b]) {
        size_t o = (size_t)(goff[b] + l) * HH + k;
        m = mu[o]; z = zlv[o];
    } else {
        m = mu_pad[k]; z = zlv_pad[k];
    }
    out[idx] = m + expf(0.5f * z) * eps[idx] + con_emb[(size_t)b * HH + k] + aff[b];
}

// kl over real node rows
__global__ __launch_bounds__(256)
void kl_node_kernel(const float* __restrict__ mu, const float* __restrict__ zlv,
                    double* kl_acc, size_t total) {
    size_t idx = (size_t)blockIdx.x * 256 + threadIdx.x;
    float v = 0.0f;
    if (idx < total) {
        float m = mu[idx], z = zlv[idx];
        v = 1.0f + z - m * m - expf(z);
    }
    __shared__ float red[256];
    red[threadIdx.x] = v;
    __syncthreads();
    for (int s = 128; s > 0; s >>= 1) {
        if (threadIdx.x < s) red[threadIdx.x] += red[threadIdx.x + s];
        __syncthreads();
    }
    if (threadIdx.x == 0) atomicAdd(kl_acc, (double)red[0]);
}

__global__ void kl_final_kernel(const double* kl_acc, float* out) {
    if (threadIdx.x == 0) out[0] = (float)(-0.5 * (*kl_acc) / 64.0);
}

// global max pool per graph (nodes of graph b are contiguous)
__global__ __launch_bounds__(384)
void pool_kernel(const float* __restrict__ h3, const int* __restrict__ goff,
                 const int* __restrict__ nn, float* __restrict__ x2) {
    int b = blockIdx.x;
    int f = threadIdx.x;
    if (f >= HH) return;
    int off = goff[b], sz = nn[b];
    float m = h3[(size_t)off * HH + f];
    for (int l = 1; l < sz; ++l)
        m = fmaxf(m, h3[(size_t)(off + l) * HH + f]);
    x2[(size_t)b * HH + f] = m;
}

// ---------------------------------------------------------------------------
extern "C" void kernel_launch(void* const* d_in, const int* in_sizes, int n_in,
                              void* d_out, int out_size, void* d_ws, size_t ws_size,
                              hipStream_t stream) {
    // inputs (setup_inputs order)
    const float* x      = (const float*)d_in[0];
    const float* con    = (const float*)d_in[1];
    const float* aff    = (const float*)d_in[2];
    const float* eps    = (const float*)d_in[3];
    const int*   eidx   = (const int*)  d_in[4];
    const int*   nn     = (const int*)  d_in[6];
    const float* seg    = (const float*)d_in[8];
    const float* W1     = (const float*)d_in[9];
    const float* b1     = (const float*)d_in[10];
    const float* W2     = (const float*)d_in[11];
    const float* b2     = (const float*)d_in[12];
    const float* W3     = (const float*)d_in[13];
    const float* b3     = (const float*)d_in[14];
    const float* condW  = (const float*)d_in[15];
    const float* condB  = (const float*)d_in[16];
    const float* mW1    = (const float*)d_in[17];
    const float* mb1    = (const float*)d_in[18];
    const float* mW2    = (const float*)d_in[19];
    const float* mb2    = (const float*)d_in[20];
    const float* vW1    = (const float*)d_in[21];
    const float* vb1    = (const float*)d_in[22];
    const float* vW2    = (const float*)d_in[23];
    const float* vb2    = (const float*)d_in[24];
    const float* fc1W   = (const float*)d_in[25];
    const float* fc1b   = (const float*)d_in[26];
    const float* fc2W   = (const float*)d_in[27];
    const float* fc2b   = (const float*)d_in[28];

    const int N = in_sizes[0] / DF_;          // 81725
    const int E = in_sizes[4] / 2;            // 326900
    const int* erow = eidx;
    const int* ecol = eidx + E;
    const int n_pad_rows = LL * BB - N;       // 49347

    // output layout (flat, return order)
    const size_t dseqN = (size_t)LL * BB * HH;       // 49,283,072
    float* out_dseq = (float*)d_out;
    float* out_amvo = out_dseq + dseqN;
    float* out_mask = out_amvo + dseqN;
    float* out_pmvo = out_mask + (size_t)BB * LL;
    float* out_kl   = out_pmvo + (size_t)BB * FIN;

    // workspace carve
    char* p = (char*)d_ws;
    size_t off = 0;
    auto alloc = [&](size_t bytes) -> char* {
        char* q = p + off;
        off = (off + bytes + 255) & ~(size_t)255;
        return q;
    };
    float*  dinv    = (float*) alloc((size_t)N * 4);
    int*    goff    = (int*)   alloc((size_t)(BB + 1) * 4);
    float*  mu_pad  = (float*) alloc(HH * 4);
    float*  zlv_pad = (float*) alloc(HH * 4);
    double* kl_acc  = (double*)alloc(8);
    float*  con_emb = (float*) alloc((size_t)BB * HH * 4);
    float*  x2      = (float*) alloc((size_t)BB * HH * 4);
    float*  tfc     = (float*) alloc((size_t)BB * 1024 * 4);
    float*  buf0    = (float*) alloc((size_t)N * HH * 4);
    float*  buf1    = (float*) alloc((size_t)N * HH * 4);
    float*  buf2    = (float*) alloc((size_t)N * HH * 4);
    (void)ws_size; (void)n_in; (void)out_size;

    // ---- degree / dinv / graph offsets ----
    init_deg_kernel<<<cdiv(N, 256), 256, 0, stream>>>(dinv, N);
    scan_kernel<<<1, 64, 0, stream>>>(nn, goff, kl_acc);
    count_deg_kernel<<<cdiv(E, 256), 256, 0, stream>>>(ecol, dinv, E);
    finalize_dinv_kernel<<<cdiv(N, 256), 256, 0, stream>>>(dinv, N);

    // ---- GCN layer 1: 94 -> 188 ----
    gemm(stream, x, W1, nullptr, nullptr, buf0, N, DF_, 2 * DF_, 0, 1);
    combine_init_kernel<<<cdiv(N * 2 * DF_, 256), 256, 0, stream>>>(buf0, dinv, b1, buf1, N, 2 * DF_);
    scatter_kernel<<<(int)(((size_t)E * 2 * DF_ + 255) / 256), 256, 0, stream>>>(erow, ecol, dinv, buf0, buf1, E, 2 * DF_);
    relu_kernel<<<cdiv(N * 2 * DF_, 256), 256, 0, stream>>>(buf1, (size_t)N * 2 * DF_);

    // ---- GCN layer 2: 188 -> 282 ----
    gemm(stream, buf1, W2, nullptr, nullptr, buf0, N, 2 * DF_, 3 * DF_, 0, 1);
    combine_init_kernel<<<cdiv(N * 3 * DF_, 256), 256, 0, stream>>>(buf0, dinv, b2, buf1, N, 3 * DF_);
    scatter_kernel<<<(int)(((size_t)E * 3 * DF_ + 255) / 256), 256, 0, stream>>>(erow, ecol, dinv, buf0, buf1, E, 3 * DF_);
    relu_kernel<<<cdiv(N * 3 * DF_, 256), 256, 0, stream>>>(buf1, (size_t)N * 3 * DF_);

    // ---- GCN layer 3: 282 -> 376 ----
    gemm(stream, buf1, W3, nullptr, nullptr, buf0, N, 3 * DF_, HH, 0, 1);
    combine_init_kernel<<<cdiv(N * HH, 256), 256, 0, stream>>>(buf0, dinv, b3, buf1, N, HH);
    scatter_kernel<<<(int)(((size_t)E * HH + 255) / 256), 256, 0, stream>>>(erow, ecol, dinv, buf0, buf1, E, HH);
    relu_kernel<<<cdiv(N * HH, 256), 256, 0, stream>>>(buf1, (size_t)N * HH);
    // h3 = buf1

    // ---- outputs depending only on h3 ----
    dseq_kernel<<<(int)((dseqN + 255) / 256), 256, 0, stream>>>(buf1, seg, nn, goff, out_dseq, dseqN);
    mask_kernel<<<cdiv(BB * LL, 256), 256, 0, stream>>>(nn, out_mask);
    pool_kernel<<<BB, 384, 0, stream>>>(buf1, goff, nn, x2);

    // ---- mu / logvar over real rows only (pad rows handled analytically) ----
    gemm(stream, buf1, mW1, mb1, seg, buf0, N, HH, HH, 1, 1);   // t1m = relu((h3+seg)@mW1+mb1)
    gemm(stream, buf0, mW2, mb2, nullptr, buf2, N, HH, HH, 0, 1); // mu -> buf2
    gemm(stream, buf1, vW1, vb1, seg, buf0, N, HH, HH, 1, 1);   // t1v (h3 still needed until here)
    gemm(stream, buf0, vW2, vb2, nullptr, buf1, N, HH, HH, 2, 1); // zlv = -|logvar| -> buf1

    // ---- pad-row vectors + exact pad kl ----
    pad_vec_kernel<<<1, 384, 0, stream>>>(seg, mW1, mb1, mW2, mb2, vW1, vb1, vW2, vb2,
                                          mu_pad, zlv_pad, kl_acc, n_pad_rows);

    // ---- conditioning embedding: con @ condW + condB (split-K atomic) ----
    init_bias_kernel<<<cdiv(BB * HH, 256), 256, 0, stream>>>(con_emb, condB, (size_t)BB * HH, HH);
    gemm(stream, con, condW, nullptr, nullptr, con_emb, BB, 96 * 107, HH, 3, 16);

    // ---- amvo ----
    amvo_kernel<<<(int)((dseqN + 255) / 256), 256, 0, stream>>>(
        buf2, buf1, mu_pad, zlv_pad, con_emb, aff, eps, nn, goff, out_amvo, dseqN);

    // ---- kl ----
    kl_node_kernel<<<(int)(((size_t)N * HH + 255) / 256), 256, 0, stream>>>(buf2, buf1, kl_acc, (size_t)N * HH);
    kl_final_kernel<<<1, 64, 0, stream>>>(kl_acc, out_kl);

    // ---- pmvo head ----
    gemm(stream, x2, fc1W, fc1b, nullptr, tfc, BB, HH, 1024, 1, 1);
    init_bias_kernel<<<cdiv(BB * FIN, 256), 256, 0, stream>>>(out_pmvo, fc2b, (size_t)BB * FIN, FIN);
    gemm(stream, tfc, fc2W, nullptr, nullptr, out_pmvo, BB, 1024, FIN, 3, 4);
}

// Round 2
// 3054.030 us; speedup vs baseline: 2.1242x; 2.1242x over previous
//
#include <hip/hip_runtime.h>
#include <hip/hip_bf16.h>
#include <math.h>

typedef unsigned short u16;
typedef __attribute__((ext_vector_type(8))) short bf16x8;
typedef __attribute__((ext_vector_type(4))) float f32x4;

// Problem constants
constexpr int BB   = 2048;
constexpr int DF_  = 94;
constexpr int HH   = 376;
constexpr int LL   = 64;
constexpr int FIN  = 256;
constexpr float PADV = -999.0f;

static inline int cdiv(int a, int b) { return (a + b - 1) / b; }

__device__ __forceinline__ u16 f2bf(float v) {
    union { float f; unsigned u; } c; c.f = v;
    unsigned r = c.u + 0x7FFF + ((c.u >> 16) & 1);   // RNE
    return (u16)(r >> 16);
}

// ---------------------------------------------------------------------------
// small kernels
// ---------------------------------------------------------------------------
__global__ __launch_bounds__(256)
void init_deg_kernel(float* deg, int N) {
    int i = blockIdx.x * 256 + threadIdx.x;
    if (i < N) deg[i] = 1.0f;
}

__global__ __launch_bounds__(256)
void count_deg_kernel(const int* __restrict__ col, float* deg, int E) {
    int e = blockIdx.x * 256 + threadIdx.x;
    if (e < E) atomicAdd(&deg[col[e]], 1.0f);
}

__global__ __launch_bounds__(256)
void finalize_dinv_kernel(float* deg, int N) {
    int i = blockIdx.x * 256 + threadIdx.x;
    if (i < N) deg[i] = rsqrtf(deg[i]);
}

__global__ void scan_kernel(const int* __restrict__ nn, int* goff, double* kl_acc) {
    if (threadIdx.x == 0) {
        int s = 0;
        for (int b = 0; b < BB; ++b) { goff[b] = s; s += nn[b]; }
        goff[BB] = s;
        *kl_acc = 0.0;
    }
}

__global__ __launch_bounds__(256)
void combine_init_kernel(const float* __restrict__ hw, const float* __restrict__ dinv,
                         const float* __restrict__ bias, float* __restrict__ out,
                         int N, int F) {
    size_t idx = (size_t)blockIdx.x * 256 + threadIdx.x;
    if (idx >= (size_t)N * F) return;
    int n = (int)(idx / F), f = (int)(idx % F);
    float di = dinv[n];
    out[idx] = di * di * hw[idx] + bias[f];
}

__global__ __launch_bounds__(256)
void scatter_kernel(const int* __restrict__ row, const int* __restrict__ col,
                    const float* __restrict__ dinv, const float* __restrict__ hw,
                    float* __restrict__ out, int E, int F) {
    size_t idx = (size_t)blockIdx.x * 256 + threadIdx.x;
    if (idx >= (size_t)E * F) return;
    int e = (int)(idx / F), f = (int)(idx % F);
    int r = row[e], d = col[e];
    atomicAdd(&out[(size_t)d * F + f], dinv[r] * dinv[d] * hw[(size_t)r * F + f]);
}

__global__ __launch_bounds__(256)
void relu_kernel(float* __restrict__ x, size_t total) {
    size_t idx = (size_t)blockIdx.x * 256 + threadIdx.x;
    if (idx < total) x[idx] = fmaxf(x[idx], 0.0f);
}

__global__ __launch_bounds__(256)
void init_bias_kernel(float* __restrict__ out, const float* __restrict__ bias,
                      size_t total, int F) {
    size_t idx = (size_t)blockIdx.x * 256 + threadIdx.x;
    if (idx < total) out[idx] = bias[idx % F];
}

// f32 [M][F] (+optional rowvec, optional relu) -> bf16 [M][Fpad], pad cols = 0
template<bool RELU>
__global__ __launch_bounds__(256)
void cast_pad_kernel(const float* __restrict__ in, const float* __restrict__ rowvec,
                     u16* __restrict__ out, int M, int F, int Fpad) {
    size_t idx = (size_t)blockIdx.x * 256 + threadIdx.x;
    if (idx >= (size_t)M * Fpad) return;
    int f = (int)(idx % Fpad);
    size_t m = idx / Fpad;
    float v = 0.0f;
    if (f < F) {
        v = in[m * F + f];
        if (rowvec) v += rowvec[f];
        if (RELU) v = fmaxf(v, 0.0f);
    }
    out[idx] = f2bf(v);
}

// W [K][Nn] f32 -> WT [Npad][Kpad] bf16 (transposed, zero-padded)
__global__ __launch_bounds__(256)
void transpose_cast_kernel(const float* __restrict__ W, u16* __restrict__ out,
                           int K, int Nn, int Kpad, int Npad) {
    __shared__ float t[32][33];
    int tx = threadIdx.x & 31, ty = threadIdx.x >> 5;
    int gk = blockIdx.x * 32, gn = blockIdx.y * 32;
    #pragma unroll
    for (int r = 0; r < 4; ++r) {
        int row = gk + ty + r * 8, col = gn + tx;
        t[ty + r * 8][tx] = (row < K && col < Nn) ? W[(size_t)row * Nn + col] : 0.0f;
    }
    __syncthreads();
    #pragma unroll
    for (int r = 0; r < 4; ++r) {
        int n = gn + ty + r * 8, k = gk + tx;
        if (n < Npad && k < Kpad) out[(size_t)n * Kpad + k] = f2bf(t[tx][ty + r * 8]);
    }
}

// ---------------------------------------------------------------------------
// bf16 MFMA GEMM: C[M,Nn] = epi(A[M,KA]bf16 @ BT[NallocB,KA]bf16^T + bias)
// tile 128x128, BK=32, 4 waves (2x2), 16x16x32 MFMA, XOR-swizzled LDS.
// MODE: 0 = f32 store (+opt bias), 1 = f32 -|v+bias|, 2 = bf16 relu(v+bias)
//       with zero-fill of pad cols [Nn,Ldc), 3 = f32 atomicAdd (split-K)
// ---------------------------------------------------------------------------
__device__ __forceinline__ int lds_swz(int row, int u) {
    return u ^ (row & 3) ^ ((row >> 2) & 3);
}

template<int MODE>
__global__ __launch_bounds__(256)
void mfma_gemm_kernel(const u16* __restrict__ A, const u16* __restrict__ BT,
                      const float* __restrict__ bias, void* __restrict__ Cout,
                      int M, int Nn, int KA, int Ldc, int NallocB, int Kchunk) {
    __shared__ uint4 As[512];   // 128 rows x 32 bf16 (64B/row), swizzled 16B units
    __shared__ uint4 Bs[512];

    const int tid  = threadIdx.x;
    const int lid  = tid & 63;
    const int wave = tid >> 6;
    const int wr   = (wave >> 1) * 64;
    const int wc   = (wave & 1) * 64;
    const int bn   = blockIdx.x * 128;
    const int bm   = blockIdx.y * 128;
    const int k0   = blockIdx.z * Kchunk;
    const int k1   = min(KA, k0 + Kchunk);

    // staging geometry (fixed per thread): slot s covers LDS row s/4, 16B-unit s%4
    int wb[2];
    const u16* gA[2];
    const u16* gB[2];
    #pragma unroll
    for (int it = 0; it < 2; ++it) {
        int s = tid + it * 256;
        int row = s >> 2, u = s & 3;
        wb[it] = row * 64 + (lds_swz(row, u) << 4);
        int ra = bm + row; ra = ra < M ? ra : M - 1;
        int rb = bn + row; rb = rb < NallocB ? rb : NallocB - 1;
        gA[it] = A  + (size_t)ra * KA + u * 8;
        gB[it] = BT + (size_t)rb * KA + u * 8;
    }

    f32x4 acc[4][4];
    #pragma unroll
    for (int i = 0; i < 4; ++i)
        #pragma unroll
        for (int j = 0; j < 4; ++j)
            acc[i][j] = (f32x4){0.0f, 0.0f, 0.0f, 0.0f};

    uint4 sa[2], sb[2];
    if (k0 < k1) {
        #pragma unroll
        for (int it = 0; it < 2; ++it) {
            sa[it] = *(const uint4*)(gA[it] + k0);
            sb[it] = *(const uint4*)(gB[it] + k0);
        }
    }

    const int ku  = lid >> 4;
    const int rlo = lid & 15;
    char* cAs = (char*)As;
    char* cBs = (char*)Bs;

    for (int kk = k0; kk < k1; kk += 32) {
        __syncthreads();
        *(uint4*)(cAs + wb[0]) = sa[0];
        *(uint4*)(cAs + wb[1]) = sa[1];
        *(uint4*)(cBs + wb[0]) = sb[0];
        *(uint4*)(cBs + wb[1]) = sb[1];
        __syncthreads();
        if (kk + 32 < k1) {   // prefetch next K-step (overlaps with MFMA below)
            #pragma unroll
            for (int it = 0; it < 2; ++it) {
                sa[it] = *(const uint4*)(gA[it] + kk + 32);
                sb[it] = *(const uint4*)(gB[it] + kk + 32);
            }
        }
        bf16x8 aF[4], bF[4];
        #pragma unroll
        for (int i = 0; i < 4; ++i) {
            int row = wr + i * 16 + rlo;
            aF[i] = *(const bf16x8*)(cAs + row * 64 + (lds_swz(row, ku) << 4));
        }
        #pragma unroll
        for (int j = 0; j < 4; ++j) {
            int row = wc + j * 16 + rlo;
            bF[j] = *(const bf16x8*)(cBs + row * 64 + (lds_swz(row, ku) << 4));
        }
        #pragma unroll
        for (int i = 0; i < 4; ++i)
            #pragma unroll
            for (int j = 0; j < 4; ++j)
                acc[i][j] = __builtin_amdgcn_mfma_f32_16x16x32_bf16(aF[i], bF[j], acc[i][j], 0, 0, 0);
    }

    // epilogue: D elem (row = 4*(lid/16)+reg, col = lid%16) within each 16x16 frag
    float* Cf = (float*)Cout;
    u16*   Cb = (u16*)Cout;
    const int rq = lid >> 4;
    #pragma unroll
    for (int i = 0; i < 4; ++i) {
        #pragma unroll
        for (int r = 0; r < 4; ++r) {
            int m = bm + wr + i * 16 + rq * 4 + r;
            if (m >= M) continue;
            #pragma unroll
            for (int j = 0; j < 4; ++j) {
                int n = bn + wc + j * 16 + rlo;
                float v = acc[i][j][r];
                if (MODE == 3) {
                    if (n < Nn) atomicAdd(&Cf[(size_t)m * Ldc + n], v);
                } else if (MODE == 2) {
                    if (n < Ldc) {
                        float o = 0.0f;
                        if (n < Nn) o = fmaxf(v + (bias ? bias[n] : 0.0f), 0.0f);
                        Cb[(size_t)m * Ldc + n] = f2bf(o);
                    }
                } else {
                    if (n < Nn) {
                        if (bias) v += bias[n];
                        if (MODE == 1) v = -fabsf(v);
                        Cf[(size_t)m * Ldc + n] = v;
                    }
                }
            }
        }
    }
}

template<int MODE>
static void mgemm(hipStream_t s, const u16* A, const u16* BT, const float* bias,
                  void* C, int M, int Nn, int KA, int Ldc, int NallocB, int splitk) {
    int ncols = (MODE == 2) ? Ldc : Nn;
    dim3 grid(cdiv(ncols, 128), cdiv(M, 128), splitk);
    int Kchunk = (cdiv(KA, splitk) + 31) & ~31;
    mfma_gemm_kernel<MODE><<<grid, 256, 0, s>>>(A, BT, bias, C, M, Nn, KA, Ldc, NallocB, Kchunk);
}

// ---------------------------------------------------------------------------
// pad-row mu/zlv + exact pad kl contribution (fp32, computed once)
// ---------------------------------------------------------------------------
__global__ __launch_bounds__(384)
void pad_vec_kernel(const float* __restrict__ seg,
                    const float* __restrict__ mW1, const float* __restrict__ mb1,
                    const float* __restrict__ mW2, const float* __restrict__ mb2,
                    const float* __restrict__ vW1, const float* __restrict__ vb1,
                    const float* __restrict__ vW2, const float* __restrict__ vb2,
                    float* __restrict__ mu_pad, float* __restrict__ zlv_pad,
                    double* kl_acc, int n_pad_rows) {
    __shared__ float t1[HH], t2[HH], red[HH];
    int j = threadIdx.x;
    if (j < HH) {
        float s1 = mb1[j], s2 = vb1[j];
        for (int k = 0; k < HH; ++k) {
            float p = PADV + seg[k];
            s1 += p * mW1[k * HH + j];
            s2 += p * vW1[k * HH + j];
        }
        t1[j] = fmaxf(s1, 0.0f);
        t2[j] = fmaxf(s2, 0.0f);
    }
    __syncthreads();
    if (j < HH) {
        float m = mb2[j], v = vb2[j];
        for (int k = 0; k < HH; ++k) {
            m += t1[k] * mW2[k * HH + j];
            v += t2[k] * vW2[k * HH + j];
        }
        float z = -fabsf(v);
        mu_pad[j]  = m;
        zlv_pad[j] = z;
        red[j] = 1.0f + z - m * m - expf(z);
    }
    __syncthreads();
    if (j == 0) {
        double s = 0.0;
        for (int k = 0; k < HH; ++k) s += (double)red[k];
        atomicAdd(kl_acc, s * (double)n_pad_rows);
    }
}

__global__ __launch_bounds__(256)
void dseq_kernel(const float* __restrict__ h3, const float* __restrict__ seg,
                 const int* __restrict__ nn, const int* __restrict__ goff,
                 float* __restrict__ out, size_t total) {
    size_t idx = (size_t)blockIdx.x * 256 + threadIdx.x;
    if (idx >= total) return;
    int k = (int)(idx % HH);
    size_t rowi = idx / HH;
    int b = (int)(rowi % BB);
    int l = (int)(rowi / BB);
    float v = (l < nn[b]) ? h3[(size_t)(goff[b] + l) * HH + k] : PADV;
    out[idx] = v + seg[k];
}

__global__ __launch_bounds__(256)
void mask_kernel(const int* __restrict__ nn, float* __restrict__ out) {
    int idx = blockIdx.x * 256 + threadIdx.x;
    if (idx >= BB * LL) return;
    int b = idx / LL, l = idx % LL;
    out[idx] = (l >= nn[b]) ? 1.0f : 0.0f;
}

// fused amvo + kl(real rows): grid-stride, per-block partial -> kl_part
__global__ __launch_bounds__(256)
void amvo_kl_kernel(const float* __restrict__ mu, const float* __restrict__ zlv,
                    const float* __restrict__ mu_pad, const float* __restrict__ zlv_pad,
                    const float* __restrict__ con_emb, const float* __restrict__ aff,
                    const float* __restrict__ eps,
                    const int* __restrict__ nn, const int* __restrict__ goff,
                    float* __restrict__ out, float* __restrict__ kl_part, size_t total) {
    float kls = 0.0f;
    for (size_t idx = (size_t)blockIdx.x * 256 + threadIdx.x; idx < total;
         idx += (size_t)gridDim.x * 256) {
        int k = (int)(idx % HH);
        size_t rowi = idx / HH;
        int b = (int)(rowi % BB);
        int l = (int)(rowi / BB);
        float m, z;
        if (l < nn[b]) {
            size_t o = (size_t)(goff[b] + l) * HH + k;
            m = mu[o]; z = zlv[o];
            kls += 1.0f + z - m * m - expf(z);
        } else {
            m = mu_pad[k]; z = zlv_pad[k];
        }
        out[idx] = m + expf(0.5f * z) * eps[idx] + con_emb[(size_t)b * HH + k] + aff[b];
    }
    __shared__ float red[256];
    red[threadIdx.x] = kls;
    __syncthreads();
    for (int s = 128; s > 0; s >>= 1) {
        if (threadIdx.x < s) red[threadIdx.x] += red[threadIdx.x + s];
        __syncthreads();
    }
    if (threadIdx.x == 0) kl_part[blockIdx.x] = red[0];
}

__global__ __launch_bounds__(256)
void kl_final_kernel(const float* __restrict__ kl_part, int nparts,
                     const double* __restrict__ kl_acc, float* __restrict__ out) {
    __shared__ double red[256];
    double s = 0.0;
    for (int i = threadIdx.x; i < nparts; i += 256) s += (double)kl_part[i];
    red[threadIdx.x] = s;
    __syncthreads();
    for (int st = 128; st > 0; st >>= 1) {
        if (threadIdx.x < st) red[threadIdx.x] += red[threadIdx.x + st];
        __syncthreads();
    }
    if (threadIdx.x == 0) out[0] = (float)(-0.5 * (red[0] + *kl_acc) / 64.0);
}

// global max pool -> bf16 [BB][384] (pad cols zero)
__global__ __launch_bounds__(384)
void pool_kernel(const float* __restrict__ h3, const int* __restrict__ goff,
                 const int* __restrict__ nn, u16* __restrict__ x2b) {
    int b = blockIdx.x;
    int f = threadIdx.x;   // 0..383
    float m = 0.0f;
    if (f < HH) {
        int off = goff[b], sz = nn[b];
        m = h3[(size_t)off * HH + f];
        for (int l = 1; l < sz; ++l)
            m = fmaxf(m, h3[(size_t)(off + l) * HH + f]);
    }
    x2b[(size_t)b * 384 + f] = f2bf(m);
}

// ---------------------------------------------------------------------------
extern "C" void kernel_launch(void* const* d_in, const int* in_sizes, int n_in,
                              void* d_out, int out_size, void* d_ws, size_t ws_size,
                              hipStream_t stream) {
    const float* x      = (const float*)d_in[0];
    const float* con    = (const float*)d_in[1];
    const float* aff    = (const float*)d_in[2];
    const float* eps    = (const float*)d_in[3];
    const int*   eidx   = (const int*)  d_in[4];
    const int*   nn     = (const int*)  d_in[6];
    const float* seg    = (const float*)d_in[8];
    const float* W1     = (const float*)d_in[9];
    const float* b1     = (const float*)d_in[10];
    const float* W2     = (const float*)d_in[11];
    const float* b2     = (const float*)d_in[12];
    const float* W3     = (const float*)d_in[13];
    const float* b3     = (const float*)d_in[14];
    const float* condW  = (const float*)d_in[15];
    const float* condB  = (const float*)d_in[16];
    const float* mW1    = (const float*)d_in[17];
    const float* mb1    = (const float*)d_in[18];
    const float* mW2    = (const float*)d_in[19];
    const float* mb2    = (const float*)d_in[20];
    const float* vW1    = (const float*)d_in[21];
    const float* vb1    = (const float*)d_in[22];
    const float* vW2    = (const float*)d_in[23];
    const float* vb2    = (const float*)d_in[24];
    const float* fc1W   = (const float*)d_in[25];
    const float* fc1b   = (const float*)d_in[26];
    const float* fc2W   = (const float*)d_in[27];
    const float* fc2b   = (const float*)d_in[28];

    const int N = in_sizes[0] / DF_;          // 81725
    const int E = in_sizes[4] / 2;            // 326900
    const int* erow = eidx;
    const int* ecol = eidx + E;
    const int n_pad_rows = LL * BB - N;

    // output layout
    const size_t dseqN = (size_t)LL * BB * HH;
    float* out_dseq = (float*)d_out;
    float* out_amvo = out_dseq + dseqN;
    float* out_mask = out_amvo + dseqN;
    float* out_pmvo = out_mask + (size_t)BB * LL;
    float* out_kl   = out_pmvo + (size_t)BB * FIN;

    // ---- workspace carve ----
    char* p = (char*)d_ws;
    size_t off = 0;
    auto alloc = [&](size_t bytes) -> char* {
        char* q = p + off;
        off = (off + bytes + 255) & ~(size_t)255;
        return q;
    };
    float*  dinv    = (float*) alloc((size_t)N * 4);
    int*    goff    = (int*)   alloc((size_t)(BB + 1) * 4);
    float*  mu_pad  = (float*) alloc(HH * 4);
    float*  zlv_pad = (float*) alloc(HH * 4);
    double* kl_acc  = (double*)alloc(8);
    float*  kl_part = (float*) alloc(2048 * 4);
    float*  con_emb = (float*) alloc((size_t)BB * HH * 4);
    u16*    x2b     = (u16*)   alloc((size_t)BB * 384 * 2);
    u16*    tfcb    = (u16*)   alloc((size_t)BB * 1024 * 2);
    u16*    W1T     = (u16*)   alloc((size_t)192 * 96 * 2);
    u16*    W2T     = (u16*)   alloc((size_t)288 * 192 * 2);
    u16*    W3T     = (u16*)   alloc((size_t)384 * 288 * 2);
    u16*    mW1T    = (u16*)   alloc((size_t)384 * 384 * 2);
    u16*    mW2T    = (u16*)   alloc((size_t)384 * 384 * 2);
    u16*    vW1T    = (u16*)   alloc((size_t)384 * 384 * 2);
    u16*    vW2T    = (u16*)   alloc((size_t)384 * 384 * 2);
    u16*    condWT  = (u16*)   alloc((size_t)384 * 10272 * 2);
    u16*    fc1WT   = (u16*)   alloc((size_t)1024 * 384 * 2);
    u16*    fc2WT   = (u16*)   alloc((size_t)256 * 1024 * 2);
    u16*    A0b     = (u16*)   alloc((size_t)N * 384 * 2);
    float*  buf0    = (float*) alloc((size_t)N * HH * 4);
    float*  buf1    = (float*) alloc((size_t)N * HH * 4);

    // large bf16 scratch lives in the (not-yet-written) amvo output region
    char* q = (char*)out_amvo;
    size_t qoff = 0;
    auto qalloc = [&](size_t bytes) -> char* {
        char* r = q + qoff;
        qoff = (qoff + bytes + 255) & ~(size_t)255;
        return r;
    };
    u16* conb = (u16*)qalloc((size_t)BB * 10272 * 2);
    u16* xb   = (u16*)qalloc((size_t)N * 96 * 2);
    u16* actb = (u16*)qalloc((size_t)N * 288 * 2);
    u16* t1b  = (u16*)qalloc((size_t)N * 384 * 2);
    (void)ws_size; (void)n_in; (void)out_size;

    // ---- degree / offsets ----
    init_deg_kernel<<<cdiv(N, 256), 256, 0, stream>>>(dinv, N);
    scan_kernel<<<1, 64, 0, stream>>>(nn, goff, kl_acc);
    count_deg_kernel<<<cdiv(E, 256), 256, 0, stream>>>(ecol, dinv, E);
    finalize_dinv_kernel<<<cdiv(N, 256), 256, 0, stream>>>(dinv, N);

    // ---- weight transposes + input casts ----
    auto tc = [&](const float* W, u16* out, int K, int Nn, int Kpad, int Npad) {
        dim3 g(cdiv(Kpad, 32), cdiv(Npad, 32));
        transpose_cast_kernel<<<g, 256, 0, stream>>>(W, out, K, Nn, Kpad, Npad);
    };
    tc(W1,   W1T,   94,    188, 96,    192);
    tc(W2,   W2T,   188,   282, 192,   288);
    tc(W3,   W3T,   282,   376, 288,   384);
    tc(mW1,  mW1T,  376,   376, 384,   384);
    tc(mW2,  mW2T,  376,   376, 384,   384);
    tc(vW1,  vW1T,  376,   376, 384,   384);
    tc(vW2,  vW2T,  376,   376, 384,   384);
    tc(condW, condWT, 10272, 376, 10272, 384);
    tc(fc1W, fc1WT, 376,   1024, 384,  1024);
    tc(fc2W, fc2WT, 1024,  256,  1024, 256);

    cast_pad_kernel<false><<<(int)(((size_t)N * 96 + 255) / 256), 256, 0, stream>>>(
        x, nullptr, xb, N, 94, 96);
    cast_pad_kernel<false><<<(int)(((size_t)BB * 10272 + 255) / 256), 256, 0, stream>>>(
        con, nullptr, conb, BB, 10272, 10272);

    // ---- GCN layer 1 ----
    mgemm<0>(stream, xb, W1T, nullptr, buf0, N, 188, 96, 188, 192, 1);
    combine_init_kernel<<<cdiv(N * 188, 256), 256, 0, stream>>>(buf0, dinv, b1, buf1, N, 188);
    scatter_kernel<<<(int)(((size_t)E * 188 + 255) / 256), 256, 0, stream>>>(erow, ecol, dinv, buf0, buf1, E, 188);
    cast_pad_kernel<true><<<(int)(((size_t)N * 192 + 255) / 256), 256, 0, stream>>>(
        buf1, nullptr, actb, N, 188, 192);

    // ---- GCN layer 2 ----
    mgemm<0>(stream, actb, W2T, nullptr, buf0, N, 282, 192, 282, 288, 1);
    combine_init_kernel<<<cdiv(N * 282, 256), 256, 0, stream>>>(buf0, dinv, b2, buf1, N, 282);
    scatter_kernel<<<(int)(((size_t)E * 282 + 255) / 256), 256, 0, stream>>>(erow, ecol, dinv, buf0, buf1, E, 282);
    cast_pad_kernel<true><<<(int)(((size_t)N * 288 + 255) / 256), 256, 0, stream>>>(
        buf1, nullptr, actb, N, 282, 288);

    // ---- GCN layer 3 ----
    mgemm<0>(stream, actb, W3T, nullptr, buf0, N, 376, 288, 376, 384, 1);
    combine_init_kernel<<<cdiv(N * HH, 256), 256, 0, stream>>>(buf0, dinv, b3, buf1, N, HH);
    scatter_kernel<<<(int)(((size_t)E * HH + 255) / 256), 256, 0, stream>>>(erow, ecol, dinv, buf0, buf1, E, HH);
    relu_kernel<<<(int)(((size_t)N * HH + 255) / 256), 256, 0, stream>>>(buf1, (size_t)N * HH);
    // h3 = buf1 (f32)

    // ---- h3-dependent outputs ----
    dseq_kernel<<<(int)((dseqN + 255) / 256), 256, 0, stream>>>(buf1, seg, nn, goff, out_dseq, dseqN);
    mask_kernel<<<cdiv(BB * LL, 256), 256, 0, stream>>>(nn, out_mask);
    pool_kernel<<<BB, 384, 0, stream>>>(buf1, goff, nn, x2b);
    cast_pad_kernel<false><<<(int)(((size_t)N * 384 + 255) / 256), 256, 0, stream>>>(
        buf1, seg, A0b, N, 376, 384);   // A0 = h3 + seg

    // ---- mu / logvar (real rows only) ----
    mgemm<2>(stream, A0b, mW1T, mb1, t1b, N, 376, 384, 384, 384, 1);
    mgemm<0>(stream, t1b, mW2T, mb2, buf0, N, 376, 384, 376, 384, 1);   // mu -> buf0
    mgemm<2>(stream, A0b, vW1T, vb1, t1b, N, 376, 384, 384, 384, 1);
    mgemm<1>(stream, t1b, vW2T, vb2, buf1, N, 376, 384, 376, 384, 1);   // zlv -> buf1

    pad_vec_kernel<<<1, 384, 0, stream>>>(seg, mW1, mb1, mW2, mb2, vW1, vb1, vW2, vb2,
                                          mu_pad, zlv_pad, kl_acc, n_pad_rows);

    // ---- conditioning embedding ----
    init_bias_kernel<<<cdiv(BB * HH, 256), 256, 0, stream>>>(con_emb, condB, (size_t)BB * HH, HH);
    mgemm<3>(stream, conb, condWT, nullptr, con_emb, BB, 376, 10272, 376, 384, 8);

    // ---- amvo + kl (fused) ----
    amvo_kl_kernel<<<2048, 256, 0, stream>>>(buf0, buf1, mu_pad, zlv_pad, con_emb, aff, eps,
                                             nn, goff, out_amvo, kl_part, dseqN);
    kl_final_kernel<<<1, 256, 0, stream>>>(kl_part, 2048, kl_acc, out_kl);

    // ---- pmvo head ----
    mgemm<2>(stream, x2b, fc1WT, fc1b, tfcb, BB, 1024, 384, 1024, 1024, 1);
    init_bias_kernel<<<cdiv(BB * FIN, 256), 256, 0, stream>>>(out_pmvo, fc2b, (size_t)BB * FIN, FIN);
    mgemm<3>(stream, tfcb, fc2WT, nullptr, out_pmvo, BB, 256, 1024, 256, 256, 8);
}

// Round 3
// 1777.837 us; speedup vs baseline: 3.6491x; 1.7178x over previous
//
#include <hip/hip_runtime.h>
#include <hip/hip_bf16.h>
#include <math.h>

typedef unsigned short u16;
typedef __attribute__((ext_vector_type(8))) short bf16x8;
typedef __attribute__((ext_vector_type(4))) float f32x4;
struct u16x4 { u16 x, y, z, w; };

// Problem constants
constexpr int BB   = 2048;
constexpr int DF_  = 94;
constexpr int HH   = 376;
constexpr int LL   = 64;
constexpr int FIN  = 256;
constexpr float PADV = -999.0f;

static inline int cdiv(int a, int b) { return (a + b - 1) / b; }

__device__ __forceinline__ u16 f2bf(float v) {
    union { float f; unsigned u; } c; c.f = v;
    unsigned r = c.u + 0x7FFF + ((c.u >> 16) & 1);   // RNE
    return (u16)(r >> 16);
}

// ---------------------------------------------------------------------------
// degree / CSR build
// ---------------------------------------------------------------------------
__global__ __launch_bounds__(256)
void zero_int_kernel(int* a, int n) {
    int i = blockIdx.x * 256 + threadIdx.x;
    if (i < n) a[i] = 0;
}

__global__ __launch_bounds__(256)
void count_deg_kernel(const int* __restrict__ col, int* deg, int E) {
    int e = blockIdx.x * 256 + threadIdx.x;
    if (e < E) atomicAdd(&deg[col[e]], 1);
}

__global__ __launch_bounds__(256)
void dinv_kernel(const int* __restrict__ deg, float* dinv, int N) {
    int i = blockIdx.x * 256 + threadIdx.x;
    if (i < N) dinv[i] = rsqrtf((float)(1 + deg[i]));
}

// block-local exclusive scan; bsum[blk] = block total
__global__ __launch_bounds__(1024)
void scan1_kernel(const int* __restrict__ deg, int N, int* __restrict__ rowptr,
                  int* __restrict__ bsum) {
    __shared__ int sh[1024];
    int t = threadIdx.x, base = blockIdx.x * 1024;
    int v = (base + t < N) ? deg[base + t] : 0;
    sh[t] = v; __syncthreads();
    for (int o = 1; o < 1024; o <<= 1) {
        int x = (t >= o) ? sh[t - o] : 0;
        __syncthreads();
        sh[t] += x;
        __syncthreads();
    }
    if (base + t < N) rowptr[base + t] = sh[t] - v;
    if (t == 1023) bsum[blockIdx.x] = sh[1023];
}

__global__ void scan2_kernel(int* bsum, int nb, int* rowptr, int N) {
    if (threadIdx.x == 0) {
        int s = 0;
        for (int i = 0; i < nb; ++i) { int v = bsum[i]; bsum[i] = s; s += v; }
        rowptr[N] = s;
    }
}

__global__ __launch_bounds__(1024)
void scan3_kernel(int* __restrict__ rowptr, int* __restrict__ cursor,
                  const int* __restrict__ bsum, int N) {
    int i = blockIdx.x * 1024 + threadIdx.x;
    if (i < N) {
        int v = rowptr[i] + bsum[blockIdx.x];
        rowptr[i] = v;
        cursor[i] = v;
    }
}

__global__ __launch_bounds__(256)
void fill_csr_kernel(const int* __restrict__ row, const int* __restrict__ col,
                     int* __restrict__ cursor, int* __restrict__ csr_src, int E) {
    int e = blockIdx.x * 256 + threadIdx.x;
    if (e < E) {
        int pos = atomicAdd(&cursor[col[e]], 1);
        csr_src[pos] = row[e];
    }
}

// goff prefix over nn (BB=2048), kl_acc init
__global__ __launch_bounds__(1024)
void goff_kernel(const int* __restrict__ nn, int* __restrict__ goff, double* kl_acc) {
    __shared__ int sh[1024];
    __shared__ int carry;
    int t = threadIdx.x;
    if (t == 0) carry = 0;
    __syncthreads();
    for (int base = 0; base < BB; base += 1024) {
        int v = nn[base + t];
        sh[t] = v; __syncthreads();
        for (int o = 1; o < 1024; o <<= 1) {
            int x = (t >= o) ? sh[t - o] : 0;
            __syncthreads();
            sh[t] += x;
            __syncthreads();
        }
        goff[base + t] = carry + sh[t] - v;
        int tot = sh[1023];
        __syncthreads();
        if (t == 0) carry += tot;
        __syncthreads();
    }
    if (t == 0) { goff[BB] = carry; *kl_acc = 0.0; }
}

// ---------------------------------------------------------------------------
// misc small kernels
// ---------------------------------------------------------------------------
__global__ __launch_bounds__(256)
void pad_f32_kernel(const float* __restrict__ in, float* __restrict__ out, int F, int Fpad) {
    int i = blockIdx.x * 256 + threadIdx.x;
    if (i < Fpad) out[i] = (i < F) ? in[i] : 0.0f;
}

__global__ __launch_bounds__(256)
void init_bias_kernel(float* __restrict__ out, const float* __restrict__ bias,
                      size_t total, int F) {
    size_t idx = (size_t)blockIdx.x * 256 + threadIdx.x;
    if (idx < total) out[idx] = bias[idx % F];
}

// f32 [M][F] -> bf16 [M][Fpad] scalar (small arrays only)
__global__ __launch_bounds__(256)
void cast_pad_kernel(const float* __restrict__ in, u16* __restrict__ out,
                     int M, int F, int Fpad) {
    size_t idx = (size_t)blockIdx.x * 256 + threadIdx.x;
    if (idx >= (size_t)M * Fpad) return;
    int f = (int)(idx % Fpad);
    size_t m = idx / Fpad;
    out[idx] = f2bf(f < F ? in[m * F + f] : 0.0f);
}

// float4 -> bf16x4 cast (no padding; total4 = elems/4)
__global__ __launch_bounds__(256)
void cast4_kernel(const float4* __restrict__ in, u16x4* __restrict__ out, int total4) {
    int idx = blockIdx.x * 256 + threadIdx.x;
    if (idx >= total4) return;
    float4 v = in[idx];
    u16x4 o; o.x = f2bf(v.x); o.y = f2bf(v.y); o.z = f2bf(v.z); o.w = f2bf(v.w);
    out[idx] = o;
}

// W [K][Nn] f32 -> WT [Npad][Kpad] bf16
__global__ __launch_bounds__(256)
void transpose_cast_kernel(const float* __restrict__ W, u16* __restrict__ out,
                           int K, int Nn, int Kpad, int Npad) {
    __shared__ float t[32][33];
    int tx = threadIdx.x & 31, ty = threadIdx.x >> 5;
    int gk = blockIdx.x * 32, gn = blockIdx.y * 32;
    #pragma unroll
    for (int r = 0; r < 4; ++r) {
        int row = gk + ty + r * 8, col = gn + tx;
        t[ty + r * 8][tx] = (row < K && col < Nn) ? W[(size_t)row * Nn + col] : 0.0f;
    }
    __syncthreads();
    #pragma unroll
    for (int r = 0; r < 4; ++r) {
        int n = gn + ty + r * 8, k = gk + tx;
        if (n < Npad && k < Kpad) out[(size_t)n * Kpad + k] = f2bf(t[tx][ty + r * 8]);
    }
}

// ---------------------------------------------------------------------------
// bf16 MFMA GEMM (128x128 tile, BK=32, 4 waves, 16x16x32)
// MODE: 0 f32 (+bias), 1 f32 -|v+bias|, 2 bf16 relu(v+bias) pad-zeroed,
//       3 f32 atomicAdd, 4 f32 pad-zeroed (no bias)
// ---------------------------------------------------------------------------
__device__ __forceinline__ int lds_swz(int row, int u) {
    return u ^ (row & 3) ^ ((row >> 2) & 3);
}

template<int MODE>
__global__ __launch_bounds__(256)
void mfma_gemm_kernel(const u16* __restrict__ A, const u16* __restrict__ BT,
                      const float* __restrict__ bias, void* __restrict__ Cout,
                      int M, int Nn, int KA, int Ldc, int NallocB, int Kchunk) {
    __shared__ uint4 As[512];
    __shared__ uint4 Bs[512];

    const int tid  = threadIdx.x;
    const int lid  = tid & 63;
    const int wave = tid >> 6;
    const int wr   = (wave >> 1) * 64;
    const int wc   = (wave & 1) * 64;
    const int bn   = blockIdx.x * 128;
    const int bm   = blockIdx.y * 128;
    const int k0   = blockIdx.z * Kchunk;
    const int k1   = min(KA, k0 + Kchunk);

    int wb[2];
    const u16* gA[2];
    const u16* gB[2];
    #pragma unroll
    for (int it = 0; it < 2; ++it) {
        int s = tid + it * 256;
        int row = s >> 2, u = s & 3;
        wb[it] = row * 64 + (lds_swz(row, u) << 4);
        int ra = bm + row; ra = ra < M ? ra : M - 1;
        int rb = bn + row; rb = rb < NallocB ? rb : NallocB - 1;
        gA[it] = A  + (size_t)ra * KA + u * 8;
        gB[it] = BT + (size_t)rb * KA + u * 8;
    }

    f32x4 acc[4][4];
    #pragma unroll
    for (int i = 0; i < 4; ++i)
        #pragma unroll
        for (int j = 0; j < 4; ++j)
            acc[i][j] = (f32x4){0.0f, 0.0f, 0.0f, 0.0f};

    uint4 sa[2], sb[2];
    if (k0 < k1) {
        #pragma unroll
        for (int it = 0; it < 2; ++it) {
            sa[it] = *(const uint4*)(gA[it] + k0);
            sb[it] = *(const uint4*)(gB[it] + k0);
        }
    }

    const int ku  = lid >> 4;
    const int rlo = lid & 15;
    char* cAs = (char*)As;
    char* cBs = (char*)Bs;

    for (int kk = k0; kk < k1; kk += 32) {
        __syncthreads();
        *(uint4*)(cAs + wb[0]) = sa[0];
        *(uint4*)(cAs + wb[1]) = sa[1];
        *(uint4*)(cBs + wb[0]) = sb[0];
        *(uint4*)(cBs + wb[1]) = sb[1];
        __syncthreads();
        if (kk + 32 < k1) {
            #pragma unroll
            for (int it = 0; it < 2; ++it) {
                sa[it] = *(const uint4*)(gA[it] + kk + 32);
                sb[it] = *(const uint4*)(gB[it] + kk + 32);
            }
        }
        bf16x8 aF[4], bF[4];
        #pragma unroll
        for (int i = 0; i < 4; ++i) {
            int row = wr + i * 16 + rlo;
            aF[i] = *(const bf16x8*)(cAs + row * 64 + (lds_swz(row, ku) << 4));
        }
        #pragma unroll
        for (int j = 0; j < 4; ++j) {
            int row = wc + j * 16 + rlo;
            bF[j] = *(const bf16x8*)(cBs + row * 64 + (lds_swz(row, ku) << 4));
        }
        #pragma unroll
        for (int i = 0; i < 4; ++i)
            #pragma unroll
            for (int j = 0; j < 4; ++j)
                acc[i][j] = __builtin_amdgcn_mfma_f32_16x16x32_bf16(aF[i], bF[j], acc[i][j], 0, 0, 0);
    }

    float* Cf = (float*)Cout;
    u16*   Cb = (u16*)Cout;
    const int rq = lid >> 4;
    #pragma unroll
    for (int i = 0; i < 4; ++i) {
        #pragma unroll
        for (int r = 0; r < 4; ++r) {
            int m = bm + wr + i * 16 + rq * 4 + r;
            if (m >= M) continue;
            #pragma unroll
            for (int j = 0; j < 4; ++j) {
                int n = bn + wc + j * 16 + rlo;
                float v = acc[i][j][r];
                if (MODE == 3) {
                    if (n < Nn) atomicAdd(&Cf[(size_t)m * Ldc + n], v);
                } else if (MODE == 2) {
                    if (n < Ldc) {
                        float o = 0.0f;
                        if (n < Nn) o = fmaxf(v + (bias ? bias[n] : 0.0f), 0.0f);
                        Cb[(size_t)m * Ldc + n] = f2bf(o);
                    }
                } else if (MODE == 4) {
                    if (n < Ldc) Cf[(size_t)m * Ldc + n] = (n < Nn) ? v : 0.0f;
                } else {
                    if (n < Nn) {
                        if (bias) v += bias[n];
                        if (MODE == 1) v = -fabsf(v);
                        Cf[(size_t)m * Ldc + n] = v;
                    }
                }
            }
        }
    }
}

template<int MODE>
static void mgemm(hipStream_t s, const u16* A, const u16* BT, const float* bias,
                  void* C, int M, int Nn, int KA, int Ldc, int NallocB, int splitk) {
    int ncols = (MODE == 2 || MODE == 4) ? Ldc : Nn;
    dim3 grid(cdiv(ncols, 128), cdiv(M, 128), splitk);
    int Kchunk = (cdiv(KA, splitk) + 31) & ~31;
    mfma_gemm_kernel<MODE><<<grid, 256, 0, s>>>(A, BT, bias, C, M, Nn, KA, Ldc, NallocB, Kchunk);
}

// ---------------------------------------------------------------------------
// fused GCN aggregation: one wave per node.
// out = relu(di*(sum_e dinv[r]*hw[r] + di*hw[n]) + bias)
// !L3: write bf16 act (padded). L3: write f32 h3 (compact 376) + bf16 (h3+seg) padded.
// ---------------------------------------------------------------------------
template<int NF4, bool L3>
__global__ __launch_bounds__(256)
void gcn_agg_kernel(const float* __restrict__ hw, const int* __restrict__ rowptr,
                    const int* __restrict__ csr_src, const float* __restrict__ dinv,
                    const float* __restrict__ biasp, u16* __restrict__ actb,
                    float* __restrict__ h3, const float* __restrict__ segp,
                    u16* __restrict__ a0b, int N) {
    int wave = threadIdx.x >> 6, lane = threadIdx.x & 63;
    int n = blockIdx.x * 4 + wave;
    if (n >= N) return;
    float di = dinv[n];
    int e0 = rowptr[n], e1 = rowptr[n + 1];
    const float4* hw4 = (const float4*)hw;
    constexpr int CH = (NF4 + 63) / 64;
    #pragma unroll
    for (int c = 0; c < CH; ++c) {
        int f4 = c * 64 + lane;
        if (f4 < NF4) {
            float4 a = hw4[(size_t)n * NF4 + f4];
            float sx = di * a.x, sy = di * a.y, sz = di * a.z, sw = di * a.w;
            for (int e = e0; e < e1; ++e) {
                int r = csr_src[e];
                float w = dinv[r];
                float4 hv = hw4[(size_t)r * NF4 + f4];
                sx = fmaf(w, hv.x, sx);
                sy = fmaf(w, hv.y, sy);
                sz = fmaf(w, hv.z, sz);
                sw = fmaf(w, hv.w, sw);
            }
            float4 b4 = ((const float4*)biasp)[f4];
            float ox = fmaxf(fmaf(di, sx, b4.x), 0.0f);
            float oy = fmaxf(fmaf(di, sy, b4.y), 0.0f);
            float oz = fmaxf(fmaf(di, sz, b4.z), 0.0f);
            float ow = fmaxf(fmaf(di, sw, b4.w), 0.0f);
            if (L3) {
                if (f4 < 94) {
                    float4 o; o.x = ox; o.y = oy; o.z = oz; o.w = ow;
                    ((float4*)h3)[(size_t)n * 94 + f4] = o;
                }
                float4 s4 = ((const float4*)segp)[f4];
                u16x4 u; u.x = f2bf(ox + s4.x); u.y = f2bf(oy + s4.y);
                u.z = f2bf(oz + s4.z); u.w = f2bf(ow + s4.w);
                ((u16x4*)a0b)[(size_t)n * NF4 + f4] = u;
            } else {
                u16x4 u; u.x = f2bf(ox); u.y = f2bf(oy); u.z = f2bf(oz); u.w = f2bf(ow);
                ((u16x4*)actb)[(size_t)n * NF4 + f4] = u;
            }
        }
    }
}

// ---------------------------------------------------------------------------
// pad-row mu/zlv + exact pad kl contribution (fp32)
// ---------------------------------------------------------------------------
__global__ __launch_bounds__(384)
void pad_vec_kernel(const float* __restrict__ seg,
                    const float* __restrict__ mW1, const float* __restrict__ mb1,
                    const float* __restrict__ mW2, const float* __restrict__ mb2,
                    const float* __restrict__ vW1, const float* __restrict__ vb1,
                    const float* __restrict__ vW2, const float* __restrict__ vb2,
                    float* __restrict__ mu_pad, float* __restrict__ zlv_pad,
                    double* kl_acc, int n_pad_rows) {
    __shared__ float t1[HH], t2[HH], red[HH];
    int j = threadIdx.x;
    if (j < HH) {
        float s1 = mb1[j], s2 = vb1[j];
        for (int k = 0; k < HH; ++k) {
            float p = PADV + seg[k];
            s1 += p * mW1[k * HH + j];
            s2 += p * vW1[k * HH + j];
        }
        t1[j] = fmaxf(s1, 0.0f);
        t2[j] = fmaxf(s2, 0.0f);
    }
    __syncthreads();
    if (j < HH) {
        float m = mb2[j], v = vb2[j];
        for (int k = 0; k < HH; ++k) {
            m += t1[k] * mW2[k * HH + j];
            v += t2[k] * vW2[k * HH + j];
        }
        float z = -fabsf(v);
        mu_pad[j]  = m;
        zlv_pad[j] = z;
        red[j] = 1.0f + z - m * m - expf(z);
    }
    __syncthreads();
    if (j == 0) {
        double s = 0.0;
        for (int k = 0; k < HH; ++k) s += (double)red[k];
        atomicAdd(kl_acc, s * (double)n_pad_rows);
    }
}

// d_seq float4 version (94 f4 per row)
__global__ __launch_bounds__(256)
void dseq4_kernel(const float* __restrict__ h3, const float* __restrict__ seg,
                  const int* __restrict__ nn, const int* __restrict__ goff,
                  float4* __restrict__ out) {
    int idx = blockIdx.x * 256 + threadIdx.x;
    if (idx >= LL * BB * 94) return;
    int k4 = idx % 94;
    int rowi = idx / 94;
    int b = rowi & (BB - 1);
    int l = rowi >> 11;
    float4 s4 = ((const float4*)seg)[k4];
    float4 v;
    if (l < nn[b]) v = ((const float4*)h3)[(size_t)(goff[b] + l) * 94 + k4];
    else { v.x = PADV; v.y = PADV; v.z = PADV; v.w = PADV; }
    float4 o; o.x = v.x + s4.x; o.y = v.y + s4.y; o.z = v.z + s4.z; o.w = v.w + s4.w;
    out[idx] = o;
}

__global__ __launch_bounds__(256)
void mask_kernel(const int* __restrict__ nn, float* __restrict__ out) {
    int idx = blockIdx.x * 256 + threadIdx.x;
    if (idx >= BB * LL) return;
    int b = idx / LL, l = idx % LL;
    out[idx] = (l >= nn[b]) ? 1.0f : 0.0f;
}

// fused amvo + kl(real rows), float4
__global__ __launch_bounds__(256)
void amvo_kl4_kernel(const float* __restrict__ mu, const float* __restrict__ zlv,
                     const float* __restrict__ mu_pad, const float* __restrict__ zlv_pad,
                     const float* __restrict__ con_emb, const float* __restrict__ aff,
                     const float4* __restrict__ eps4,
                     const int* __restrict__ nn, const int* __restrict__ goff,
                     float4* __restrict__ out, float* __restrict__ kl_part) {
    const int T4 = LL * BB * 94;
    float kls = 0.0f;
    for (int idx = blockIdx.x * 256 + threadIdx.x; idx < T4; idx += 2048 * 256) {
        int k4 = idx % 94;
        int rowi = idx / 94;
        int b = rowi & (BB - 1);
        int l = rowi >> 11;
        float4 m, z;
        if (l < nn[b]) {
            size_t o = (size_t)(goff[b] + l) * 94 + k4;
            m = ((const float4*)mu)[o];
            z = ((const float4*)zlv)[o];
            kls += (1.0f + z.x - m.x * m.x - __expf(z.x))
                 + (1.0f + z.y - m.y * m.y - __expf(z.y))
                 + (1.0f + z.z - m.z * m.z - __expf(z.z))
                 + (1.0f + z.w - m.w * m.w - __expf(z.w));
        } else {
            m = ((const float4*)mu_pad)[k4];
            z = ((const float4*)zlv_pad)[k4];
        }
        float4 e = eps4[idx];
        float4 c = ((const float4*)con_emb)[(size_t)b * 94 + k4];
        float af = aff[b];
        float4 o;
        o.x = m.x + __expf(0.5f * z.x) * e.x + c.x + af;
        o.y = m.y + __expf(0.5f * z.y) * e.y + c.y + af;
        o.z = m.z + __expf(0.5f * z.z) * e.z + c.z + af;
        o.w = m.w + __expf(0.5f * z.w) * e.w + c.w + af;
        out[idx] = o;
    }
    __shared__ float red[256];
    red[threadIdx.x] = kls;
    __syncthreads();
    for (int s = 128; s > 0; s >>= 1) {
        if (threadIdx.x < s) red[threadIdx.x] += red[threadIdx.x + s];
        __syncthreads();
    }
    if (threadIdx.x == 0) kl_part[blockIdx.x] = red[0];
}

__global__ __launch_bounds__(256)
void kl_final_kernel(const float* __restrict__ kl_part, int nparts,
                     const double* __restrict__ kl_acc, float* __restrict__ out) {
    __shared__ double red[256];
    double s = 0.0;
    for (int i = threadIdx.x; i < nparts; i += 256) s += (double)kl_part[i];
    red[threadIdx.x] = s;
    __syncthreads();
    for (int st = 128; st > 0; st >>= 1) {
        if (threadIdx.x < st) red[threadIdx.x] += red[threadIdx.x + st];
        __syncthreads();
    }
    if (threadIdx.x == 0) out[0] = (float)(-0.5 * (red[0] + *kl_acc) / 64.0);
}

// global max pool -> bf16 [BB][384]
__global__ __launch_bounds__(384)
void pool_kernel(const float* __restrict__ h3, const int* __restrict__ goff,
                 const int* __restrict__ nn, u16* __restrict__ x2b) {
    int b = blockIdx.x;
    int f = threadIdx.x;
    float m = 0.0f;
    if (f < HH) {
        int off = goff[b], sz = nn[b];
        m = h3[(size_t)off * HH + f];
        for (int l = 1; l < sz; ++l)
            m = fmaxf(m, h3[(size_t)(off + l) * HH + f]);
    }
    x2b[(size_t)b * 384 + f] = f2bf(m);
}

// ---------------------------------------------------------------------------
extern "C" void kernel_launch(void* const* d_in, const int* in_sizes, int n_in,
                              void* d_out, int out_size, void* d_ws, size_t ws_size,
                              hipStream_t stream) {
    const float* x      = (const float*)d_in[0];
    const float* con    = (const float*)d_in[1];
    const float* aff    = (const float*)d_in[2];
    const float* eps    = (const float*)d_in[3];
    const int*   eidx   = (const int*)  d_in[4];
    const int*   nn     = (const int*)  d_in[6];
    const float* seg    = (const float*)d_in[8];
    const float* W1     = (const float*)d_in[9];
    const float* b1     = (const float*)d_in[10];
    const float* W2     = (const float*)d_in[11];
    const float* b2     = (const float*)d_in[12];
    const float* W3     = (const float*)d_in[13];
    const float* b3     = (const float*)d_in[14];
    const float* condW  = (const float*)d_in[15];
    const float* condB  = (const float*)d_in[16];
    const float* mW1    = (const float*)d_in[17];
    const float* mb1    = (const float*)d_in[18];
    const float* mW2    = (const float*)d_in[19];
    const float* mb2    = (const float*)d_in[20];
    const float* vW1    = (const float*)d_in[21];
    const float* vb1    = (const float*)d_in[22];
    const float* vW2    = (const float*)d_in[23];
    const float* vb2    = (const float*)d_in[24];
    const float* fc1W   = (const float*)d_in[25];
    const float* fc1b   = (const float*)d_in[26];
    const float* fc2W   = (const float*)d_in[27];
    const float* fc2b   = (const float*)d_in[28];

    const int N = in_sizes[0] / DF_;          // 81725
    const int E = in_sizes[4] / 2;            // 326900
    const int* erow = eidx;
    const int* ecol = eidx + E;
    const int n_pad_rows = LL * BB - N;

    // output layout
    const size_t dseqN = (size_t)LL * BB * HH;
    float* out_dseq = (float*)d_out;
    float* out_amvo = out_dseq + dseqN;
    float* out_mask = out_amvo + dseqN;
    float* out_pmvo = out_mask + (size_t)BB * LL;
    float* out_kl   = out_pmvo + (size_t)BB * FIN;

    // ---- workspace carve ----
    char* p = (char*)d_ws;
    size_t off = 0;
    auto alloc = [&](size_t bytes) -> char* {
        char* q = p + off;
        off = (off + bytes + 255) & ~(size_t)255;
        return q;
    };
    float*  dinv    = (float*) alloc((size_t)N * 4);
    int*    deg     = (int*)   alloc((size_t)N * 4);
    int*    rowptr  = (int*)   alloc((size_t)(N + 1) * 4);
    int*    cursor  = (int*)   alloc((size_t)N * 4);
    int*    csr_src = (int*)   alloc((size_t)E * 4);
    int*    bsum    = (int*)   alloc((size_t)128 * 4);
    int*    goff    = (int*)   alloc((size_t)(BB + 1) * 4);
    float*  mu_pad  = (float*) alloc(HH * 4);
    float*  zlv_pad = (float*) alloc(HH * 4);
    double* kl_acc  = (double*)alloc(8);
    float*  kl_part = (float*) alloc(2048 * 4);
    float*  b1p     = (float*) alloc(192 * 4);
    float*  b2p     = (float*) alloc(288 * 4);
    float*  b3p     = (float*) alloc(384 * 4);
    float*  segp    = (float*) alloc(384 * 4);
    float*  con_emb = (float*) alloc((size_t)BB * HH * 4);
    u16*    x2b     = (u16*)   alloc((size_t)BB * 384 * 2);
    u16*    tfcb    = (u16*)   alloc((size_t)BB * 1024 * 2);
    u16*    W1T     = (u16*)   alloc((size_t)192 * 96 * 2);
    u16*    W2T     = (u16*)   alloc((size_t)288 * 192 * 2);
    u16*    W3T     = (u16*)   alloc((size_t)384 * 288 * 2);
    u16*    mW1T    = (u16*)   alloc((size_t)384 * 384 * 2);
    u16*    mW2T    = (u16*)   alloc((size_t)384 * 384 * 2);
    u16*    vW1T    = (u16*)   alloc((size_t)384 * 384 * 2);
    u16*    vW2T    = (u16*)   alloc((size_t)384 * 384 * 2);
    u16*    condWT  = (u16*)   alloc((size_t)384 * 10272 * 2);
    u16*    fc1WT   = (u16*)   alloc((size_t)1024 * 384 * 2);
    u16*    fc2WT   = (u16*)   alloc((size_t)256 * 1024 * 2);
    u16*    a0b     = (u16*)   alloc((size_t)N * 384 * 2);
    float*  buf0    = (float*) alloc((size_t)N * HH * 4);   // mu
    float*  buf1    = (float*) alloc((size_t)N * HH * 4);   // h3 then zlv

    // hw GEMM scratch lives in the not-yet-written dseq output region (197 MB)
    float* hw = out_dseq;   // N x 384 f32 max = 125.5 MB

    // bf16 scratch in the not-yet-written amvo output region (197 MB)
    char* q = (char*)out_amvo;
    size_t qoff = 0;
    auto qalloc = [&](size_t bytes) -> char* {
        char* r = q + qoff;
        qoff = (qoff + bytes + 255) & ~(size_t)255;
        return r;
    };
    u16* conb = (u16*)qalloc((size_t)BB * 10272 * 2);   // 42 MB
    u16* xb   = (u16*)qalloc((size_t)N * 96 * 2);       // 15.7 MB
    u16* actb = (u16*)qalloc((size_t)N * 288 * 2);      // 47 MB
    u16* t1b  = (u16*)qalloc((size_t)N * 384 * 2);      // 62.8 MB
    (void)ws_size; (void)n_in; (void)out_size;

    // ---- degree / dinv / CSR / goff ----
    const int NB = cdiv(N, 1024);
    zero_int_kernel<<<cdiv(N, 256), 256, 0, stream>>>(deg, N);
    count_deg_kernel<<<cdiv(E, 256), 256, 0, stream>>>(ecol, deg, E);
    dinv_kernel<<<cdiv(N, 256), 256, 0, stream>>>(deg, dinv, N);
    scan1_kernel<<<NB, 1024, 0, stream>>>(deg, N, rowptr, bsum);
    scan2_kernel<<<1, 64, 0, stream>>>(bsum, NB, rowptr, N);
    scan3_kernel<<<NB, 1024, 0, stream>>>(rowptr, cursor, bsum, N);
    fill_csr_kernel<<<cdiv(E, 256), 256, 0, stream>>>(erow, ecol, cursor, csr_src, E);
    goff_kernel<<<1, 1024, 0, stream>>>(nn, goff, kl_acc);

    // ---- padded bias / seg vectors ----
    pad_f32_kernel<<<1, 256, 0, stream>>>(b1, b1p, 188, 192);
    pad_f32_kernel<<<2, 256, 0, stream>>>(b2, b2p, 282, 288);
    pad_f32_kernel<<<2, 256, 0, stream>>>(b3, b3p, 376, 384);
    pad_f32_kernel<<<2, 256, 0, stream>>>(seg, segp, 376, 384);

    // ---- weight transposes + input casts ----
    auto tc = [&](const float* W, u16* out, int K, int Nn, int Kpad, int Npad) {
        dim3 g(cdiv(Kpad, 32), cdiv(Npad, 32));
        transpose_cast_kernel<<<g, 256, 0, stream>>>(W, out, K, Nn, Kpad, Npad);
    };
    tc(W1,    W1T,    94,    188,  96,    192);
    tc(W2,    W2T,    188,   282,  192,   288);
    tc(W3,    W3T,    282,   376,  288,   384);
    tc(mW1,   mW1T,   376,   376,  384,   384);
    tc(mW2,   mW2T,   376,   376,  384,   384);
    tc(vW1,   vW1T,   376,   376,  384,   384);
    tc(vW2,   vW2T,   376,   376,  384,   384);
    tc(condW, condWT, 10272, 376,  10272, 384);
    tc(fc1W,  fc1WT,  376,   1024, 384,   1024);
    tc(fc2W,  fc2WT,  1024,  256,  1024,  256);

    cast_pad_kernel<<<(int)(((size_t)N * 96 + 255) / 256), 256, 0, stream>>>(x, xb, N, 94, 96);
    cast4_kernel<<<cdiv(BB * 10272 / 4, 256), 256, 0, stream>>>(
        (const float4*)con, (u16x4*)conb, BB * 10272 / 4);

    // ---- GCN layer 1: 94 -> 188 ----
    mgemm<4>(stream, xb, W1T, nullptr, hw, N, 188, 96, 192, 192, 1);
    gcn_agg_kernel<48, false><<<cdiv(N, 4), 256, 0, stream>>>(
        hw, rowptr, csr_src, dinv, b1p, actb, nullptr, nullptr, nullptr, N);

    // ---- GCN layer 2: 188 -> 282 ----
    mgemm<4>(stream, actb, W2T, nullptr, hw, N, 282, 192, 288, 288, 1);
    gcn_agg_kernel<72, false><<<cdiv(N, 4), 256, 0, stream>>>(
        hw, rowptr, csr_src, dinv, b2p, actb, nullptr, nullptr, nullptr, N);

    // ---- GCN layer 3: 282 -> 376 (writes f32 h3 + bf16 h3+seg) ----
    mgemm<4>(stream, actb, W3T, nullptr, hw, N, 376, 288, 384, 384, 1);
    gcn_agg_kernel<96, true><<<cdiv(N, 4), 256, 0, stream>>>(
        hw, rowptr, csr_src, dinv, b3p, nullptr, buf1, segp, a0b, N);

    // ---- h3-dependent outputs (must run before hw region is reused by dseq) ----
    dseq4_kernel<<<cdiv(LL * BB * 94, 256), 256, 0, stream>>>(buf1, seg, nn, goff, (float4*)out_dseq);
    mask_kernel<<<cdiv(BB * LL, 256), 256, 0, stream>>>(nn, out_mask);
    pool_kernel<<<BB, 384, 0, stream>>>(buf1, goff, nn, x2b);

    // ---- mu / logvar (real rows only) ----
    mgemm<2>(stream, a0b, mW1T, mb1, t1b, N, 376, 384, 384, 384, 1);
    mgemm<0>(stream, t1b, mW2T, mb2, buf0, N, 376, 384, 376, 384, 1);   // mu
    mgemm<2>(stream, a0b, vW1T, vb1, t1b, N, 376, 384, 384, 384, 1);
    mgemm<1>(stream, t1b, vW2T, vb2, buf1, N, 376, 384, 376, 384, 1);   // zlv (h3 done)

    pad_vec_kernel<<<1, 384, 0, stream>>>(seg, mW1, mb1, mW2, mb2, vW1, vb1, vW2, vb2,
                                          mu_pad, zlv_pad, kl_acc, n_pad_rows);

    // ---- conditioning embedding ----
    init_bias_kernel<<<cdiv(BB * HH, 256), 256, 0, stream>>>(con_emb, condB, (size_t)BB * HH, HH);
    mgemm<3>(stream, conb, condWT, nullptr, con_emb, BB, 376, 10272, 376, 384, 16);

    // ---- amvo + kl ----
    amvo_kl4_kernel<<<2048, 256, 0, stream>>>(buf0, buf1, mu_pad, zlv_pad, con_emb, aff,
                                              (const float4*)eps, nn, goff,
                                              (float4*)out_amvo, kl_part);
    kl_final_kernel<<<1, 256, 0, stream>>>(kl_part, 2048, kl_acc, out_kl);

    // ---- pmvo head ----
    mgemm<2>(stream, x2b, fc1WT, fc1b, tfcb, BB, 1024, 384, 1024, 1024, 1);
    init_bias_kernel<<<cdiv(BB * FIN, 256), 256, 0, stream>>>(out_pmvo, fc2b, (size_t)BB * FIN, FIN);
    mgemm<3>(stream, tfcb, fc2WT, nullptr, out_pmvo, BB, 256, 1024, 256, 256, 8);
}

// Round 4
// 1659.887 us; speedup vs baseline: 3.9084x; 1.0711x over previous
//
#include <hip/hip_runtime.h>
#include <hip/hip_bf16.h>
#include <math.h>

typedef unsigned short u16;
typedef __attribute__((ext_vector_type(8))) short bf16x8;
typedef __attribute__((ext_vector_type(4))) float f32x4;
struct __align__(8) u16x4 { u16 x, y, z, w; };

constexpr int BB   = 2048;
constexpr int DF_  = 94;
constexpr int HH   = 376;
constexpr int LL   = 64;
constexpr int FIN  = 256;
constexpr float PADV = -999.0f;

static inline int cdiv(int a, int b) { return (a + b - 1) / b; }

__device__ __forceinline__ u16 f2bf(float v) {
    union { float f; unsigned u; } c; c.f = v;
    unsigned r = c.u + 0x7FFF + ((c.u >> 16) & 1);   // RNE
    return (u16)(r >> 16);
}
__device__ __forceinline__ float bf2f(u16 v) {
    union { unsigned u; float f; } c; c.u = ((unsigned)v) << 16;
    return c.f;
}

// ---------------------------------------------------------------------------
// degree / CSR build
// ---------------------------------------------------------------------------
__global__ __launch_bounds__(256)
void zero_int_kernel(int* a, int n) {
    int i = blockIdx.x * 256 + threadIdx.x;
    if (i < n) a[i] = 0;
}

__global__ __launch_bounds__(256)
void count_deg_kernel(const int* __restrict__ col, int* deg, int E) {
    int e = blockIdx.x * 256 + threadIdx.x;
    if (e < E) atomicAdd(&deg[col[e]], 1);
}

__global__ __launch_bounds__(256)
void dinv_kernel(const int* __restrict__ deg, float* dinv, int N) {
    int i = blockIdx.x * 256 + threadIdx.x;
    if (i < N) dinv[i] = rsqrtf((float)(1 + deg[i]));
}

__global__ __launch_bounds__(1024)
void scan1_kernel(const int* __restrict__ deg, int N, int* __restrict__ rowptr,
                  int* __restrict__ bsum) {
    __shared__ int sh[1024];
    int t = threadIdx.x, base = blockIdx.x * 1024;
    int v = (base + t < N) ? deg[base + t] : 0;
    sh[t] = v; __syncthreads();
    for (int o = 1; o < 1024; o <<= 1) {
        int x = (t >= o) ? sh[t - o] : 0;
        __syncthreads();
        sh[t] += x;
        __syncthreads();
    }
    if (base + t < N) rowptr[base + t] = sh[t] - v;
    if (t == 1023) bsum[blockIdx.x] = sh[1023];
}

__global__ void scan2_kernel(int* bsum, int nb, int* rowptr, int N) {
    if (threadIdx.x == 0) {
        int s = 0;
        for (int i = 0; i < nb; ++i) { int v = bsum[i]; bsum[i] = s; s += v; }
        rowptr[N] = s;
    }
}

__global__ __launch_bounds__(1024)
void scan3_kernel(int* __restrict__ rowptr, int* __restrict__ cursor,
                  const int* __restrict__ bsum, int N) {
    int i = blockIdx.x * 1024 + threadIdx.x;
    if (i < N) {
        int v = rowptr[i] + bsum[blockIdx.x];
        rowptr[i] = v;
        cursor[i] = v;
    }
}

__global__ __launch_bounds__(256)
void fill_csr_kernel(const int* __restrict__ row, const int* __restrict__ col,
                     int* __restrict__ cursor, int* __restrict__ csr_src, int E) {
    int e = blockIdx.x * 256 + threadIdx.x;
    if (e < E) {
        int pos = atomicAdd(&cursor[col[e]], 1);
        csr_src[pos] = row[e];
    }
}

__global__ __launch_bounds__(1024)
void goff_kernel(const int* __restrict__ nn, int* __restrict__ goff, double* kl_acc) {
    __shared__ int sh[1024];
    __shared__ int carry;
    int t = threadIdx.x;
    if (t == 0) carry = 0;
    __syncthreads();
    for (int base = 0; base < BB; base += 1024) {
        int v = nn[base + t];
        sh[t] = v; __syncthreads();
        for (int o = 1; o < 1024; o <<= 1) {
            int x = (t >= o) ? sh[t - o] : 0;
            __syncthreads();
            sh[t] += x;
            __syncthreads();
        }
        goff[base + t] = carry + sh[t] - v;
        int tot = sh[1023];
        __syncthreads();
        if (t == 0) carry += tot;
        __syncthreads();
    }
    if (t == 0) { goff[BB] = carry; *kl_acc = 0.0; }
}

// ---------------------------------------------------------------------------
// misc small kernels
// ---------------------------------------------------------------------------
__global__ __launch_bounds__(256)
void pad_f32_kernel(const float* __restrict__ in, float* __restrict__ out, int F, int Fpad) {
    int i = blockIdx.x * 256 + threadIdx.x;
    if (i < Fpad) out[i] = (i < F) ? in[i] : 0.0f;
}

__global__ __launch_bounds__(256)
void init_bias_kernel(float* __restrict__ out, const float* __restrict__ bias,
                      size_t total, int F) {
    size_t idx = (size_t)blockIdx.x * 256 + threadIdx.x;
    if (idx < total) out[idx] = bias[idx % F];
}

__global__ __launch_bounds__(256)
void cast_pad_kernel(const float* __restrict__ in, u16* __restrict__ out,
                     int M, int F, int Fpad) {
    size_t idx = (size_t)blockIdx.x * 256 + threadIdx.x;
    if (idx >= (size_t)M * Fpad) return;
    int f = (int)(idx % Fpad);
    size_t m = idx / Fpad;
    out[idx] = f2bf(f < F ? in[m * F + f] : 0.0f);
}

__global__ __launch_bounds__(256)
void cast4_kernel(const float4* __restrict__ in, u16x4* __restrict__ out, int total4) {
    int idx = blockIdx.x * 256 + threadIdx.x;
    if (idx >= total4) return;
    float4 v = in[idx];
    u16x4 o; o.x = f2bf(v.x); o.y = f2bf(v.y); o.z = f2bf(v.z); o.w = f2bf(v.w);
    out[idx] = o;
}

__global__ __launch_bounds__(256)
void transpose_cast_kernel(const float* __restrict__ W, u16* __restrict__ out,
                           int K, int Nn, int Kpad, int Npad) {
    __shared__ float t[32][33];
    int tx = threadIdx.x & 31, ty = threadIdx.x >> 5;
    int gk = blockIdx.x * 32, gn = blockIdx.y * 32;
    #pragma unroll
    for (int r = 0; r < 4; ++r) {
        int row = gk + ty + r * 8, col = gn + tx;
        t[ty + r * 8][tx] = (row < K && col < Nn) ? W[(size_t)row * Nn + col] : 0.0f;
    }
    __syncthreads();
    #pragma unroll
    for (int r = 0; r < 4; ++r) {
        int n = gn + ty + r * 8, k = gk + tx;
        if (n < Npad && k < Kpad) out[(size_t)n * Kpad + k] = f2bf(t[tx][ty + r * 8]);
    }
}

// ---------------------------------------------------------------------------
// bf16 MFMA GEMM (128x128 tile, BK=32, 4 waves, 16x16x32)
// Double-buffered LDS, ONE barrier per K-step, loads 2 steps in flight.
// MODE: 0 f32 (+bias), 1 f32 -|v+bias|, 2 bf16 relu(v+bias) pad-zeroed,
//       3 f32 atomicAdd, 4 f32 pad-zeroed no bias, 5 bf16 (v+bias),
//       6 bf16 -|v+bias|
// ---------------------------------------------------------------------------
__device__ __forceinline__ int lds_swz(int row, int u) {
    return u ^ (row & 3) ^ ((row >> 2) & 3);
}

template<int MODE>
__global__ __launch_bounds__(256)
void mfma_gemm_kernel(const u16* __restrict__ A, const u16* __restrict__ BT,
                      const float* __restrict__ bias, void* __restrict__ Cout,
                      int M, int Nn, int KA, int lda, int ldb, int Ldc,
                      int NallocB, int Kchunk) {
    __shared__ uint4 As[2][512];
    __shared__ uint4 Bs[2][512];

    const int tid  = threadIdx.x;
    const int lid  = tid & 63;
    const int wave = tid >> 6;
    const int wr   = (wave >> 1) * 64;
    const int wc   = (wave & 1) * 64;
    const int bn   = blockIdx.x * 128;
    const int bm   = blockIdx.y * 128;
    const int k0   = blockIdx.z * Kchunk;
    const int k1   = min(KA, k0 + Kchunk);
    const int nt   = (k1 - k0) >> 5;   // chunk is a multiple of 32

    int wb[2];
    const u16* gA[2];
    const u16* gB[2];
    #pragma unroll
    for (int it = 0; it < 2; ++it) {
        int s = tid + it * 256;
        int row = s >> 2, u = s & 3;
        wb[it] = row * 4 + lds_swz(row, u);
        int ra = bm + row; ra = ra < M ? ra : M - 1;
        int rb = bn + row; rb = rb < NallocB ? rb : NallocB - 1;
        gA[it] = A  + (size_t)ra * lda + u * 8;
        gB[it] = BT + (size_t)rb * ldb + u * 8;
    }

    f32x4 acc[4][4];
    #pragma unroll
    for (int i = 0; i < 4; ++i)
        #pragma unroll
        for (int j = 0; j < 4; ++j)
            acc[i][j] = (f32x4){0.0f, 0.0f, 0.0f, 0.0f};

    uint4 sa[2], sb[2];
    #pragma unroll
    for (int it = 0; it < 2; ++it) {
        sa[it] = *(const uint4*)(gA[it] + k0);
        sb[it] = *(const uint4*)(gB[it] + k0);
    }
    As[0][wb[0]] = sa[0]; As[0][wb[1]] = sa[1];
    Bs[0][wb[0]] = sb[0]; Bs[0][wb[1]] = sb[1];
    if (nt > 1) {
        #pragma unroll
        for (int it = 0; it < 2; ++it) {
            sa[it] = *(const uint4*)(gA[it] + k0 + 32);
            sb[it] = *(const uint4*)(gB[it] + k0 + 32);
        }
    }

    const int ku  = lid >> 4;
    const int rlo = lid & 15;

    for (int t = 0; t < nt; ++t) {
        __syncthreads();
        const int cur = t & 1;
        if (t + 1 < nt) {
            const int nxt = cur ^ 1;
            As[nxt][wb[0]] = sa[0]; As[nxt][wb[1]] = sa[1];
            Bs[nxt][wb[0]] = sb[0]; Bs[nxt][wb[1]] = sb[1];
        }
        bf16x8 aF[4], bF[4];
        #pragma unroll
        for (int i = 0; i < 4; ++i) {
            int row = wr + i * 16 + rlo;
            aF[i] = *(const bf16x8*)&As[cur][row * 4 + lds_swz(row, ku)];
        }
        #pragma unroll
        for (int j = 0; j < 4; ++j) {
            int row = wc + j * 16 + rlo;
            bF[j] = *(const bf16x8*)&Bs[cur][row * 4 + lds_swz(row, ku)];
        }
        if (t + 2 < nt) {
            int kk = k0 + (t + 2) * 32;
            #pragma unroll
            for (int it = 0; it < 2; ++it) {
                sa[it] = *(const uint4*)(gA[it] + kk);
                sb[it] = *(const uint4*)(gB[it] + kk);
            }
        }
        #pragma unroll
        for (int i = 0; i < 4; ++i)
            #pragma unroll
            for (int j = 0; j < 4; ++j)
                acc[i][j] = __builtin_amdgcn_mfma_f32_16x16x32_bf16(aF[i], bF[j], acc[i][j], 0, 0, 0);
    }

    float* Cf = (float*)Cout;
    u16*   Cb = (u16*)Cout;
    const int rq = lid >> 4;
    #pragma unroll
    for (int i = 0; i < 4; ++i) {
        #pragma unroll
        for (int r = 0; r < 4; ++r) {
            int m = bm + wr + i * 16 + rq * 4 + r;
            if (m >= M) continue;
            #pragma unroll
            for (int j = 0; j < 4; ++j) {
                int n = bn + wc + j * 16 + rlo;
                float v = acc[i][j][r];
                if (MODE == 3) {
                    if (n < Nn) atomicAdd(&Cf[(size_t)m * Ldc + n], v);
                } else if (MODE == 2) {
                    if (n < Ldc) {
                        float o = 0.0f;
                        if (n < Nn) o = fmaxf(v + (bias ? bias[n] : 0.0f), 0.0f);
                        Cb[(size_t)m * Ldc + n] = f2bf(o);
                    }
                } else if (MODE == 4) {
                    if (n < Ldc) Cf[(size_t)m * Ldc + n] = (n < Nn) ? v : 0.0f;
                } else if (MODE == 5 || MODE == 6) {
                    if (n < Nn) {
                        float o = v + (bias ? bias[n] : 0.0f);
                        if (MODE == 6) o = -fabsf(o);
                        Cb[(size_t)m * Ldc + n] = f2bf(o);
                    }
                } else {
                    if (n < Nn) {
                        if (bias) v += bias[n];
                        if (MODE == 1) v = -fabsf(v);
                        Cf[(size_t)m * Ldc + n] = v;
                    }
                }
            }
        }
    }
}

template<int MODE>
static void mgemm(hipStream_t s, const u16* A, const u16* BT, const float* bias,
                  void* C, int M, int Nn, int KA, int lda, int ldb, int Ldc,
                  int NallocB, int splitk) {
    int ncols = (MODE == 2 || MODE == 4) ? Ldc : Nn;
    dim3 grid(cdiv(ncols, 128), cdiv(M, 128), splitk);
    int Kchunk = (cdiv(KA, splitk) + 31) & ~31;
    mfma_gemm_kernel<MODE><<<grid, 256, 0, s>>>(A, BT, bias, C, M, Nn, KA, lda, ldb,
                                                Ldc, NallocB, Kchunk);
}

// ---------------------------------------------------------------------------
// fused GCN aggregation: one wave per node.
// L3 variant additionally scatters (h3+seg) f32 into out_dseq via (pos,batch),
// writes compact bf16 h3 (for pool) and padded bf16 (h3+seg) (for stage-1 GEMM).
// ---------------------------------------------------------------------------
template<int NF4, bool L3>
__global__ __launch_bounds__(256)
void gcn_agg_kernel(const float* __restrict__ hw, const int* __restrict__ rowptr,
                    const int* __restrict__ csr_src, const float* __restrict__ dinv,
                    const float* __restrict__ biasp, u16* __restrict__ actb,
                    const float* __restrict__ segp, u16* __restrict__ h3b,
                    u16* __restrict__ a0b, const int* __restrict__ batch,
                    const int* __restrict__ pos, float4* __restrict__ dseq_out, int N) {
    int wave = threadIdx.x >> 6, lane = threadIdx.x & 63;
    int n = blockIdx.x * 4 + wave;
    if (n >= N) return;
    float di = dinv[n];
    int e0 = rowptr[n], e1 = rowptr[n + 1];
    size_t drow = 0;
    if (L3) drow = ((size_t)pos[n] * BB + batch[n]) * 94;
    const float4* hw4 = (const float4*)hw;
    constexpr int CH = (NF4 + 63) / 64;
    #pragma unroll
    for (int c = 0; c < CH; ++c) {
        int f4 = c * 64 + lane;
        if (f4 < NF4) {
            float4 a = hw4[(size_t)n * NF4 + f4];
            float sx = di * a.x, sy = di * a.y, sz = di * a.z, sw = di * a.w;
            for (int e = e0; e < e1; ++e) {
                int r = csr_src[e];
                float w = dinv[r];
                float4 hv = hw4[(size_t)r * NF4 + f4];
                sx = fmaf(w, hv.x, sx);
                sy = fmaf(w, hv.y, sy);
                sz = fmaf(w, hv.z, sz);
                sw = fmaf(w, hv.w, sw);
            }
            float4 b4 = ((const float4*)biasp)[f4];
            float ox = fmaxf(fmaf(di, sx, b4.x), 0.0f);
            float oy = fmaxf(fmaf(di, sy, b4.y), 0.0f);
            float oz = fmaxf(fmaf(di, sz, b4.z), 0.0f);
            float ow = fmaxf(fmaf(di, sw, b4.w), 0.0f);
            if (L3) {
                float4 s4 = ((const float4*)segp)[f4];
                float dx = ox + s4.x, dy = oy + s4.y, dz = oz + s4.z, dw = ow + s4.w;
                u16x4 ud; ud.x = f2bf(dx); ud.y = f2bf(dy); ud.z = f2bf(dz); ud.w = f2bf(dw);
                ((u16x4*)a0b)[(size_t)n * NF4 + f4] = ud;
                if (f4 < 94) {
                    float4 d; d.x = dx; d.y = dy; d.z = dz; d.w = dw;
                    dseq_out[drow + f4] = d;
                    u16x4 uh; uh.x = f2bf(ox); uh.y = f2bf(oy); uh.z = f2bf(oz); uh.w = f2bf(ow);
                    ((u16x4*)h3b)[(size_t)n * 94 + f4] = uh;
                }
            } else {
                u16x4 u; u.x = f2bf(ox); u.y = f2bf(oy); u.z = f2bf(oz); u.w = f2bf(ow);
                ((u16x4*)actb)[(size_t)n * NF4 + f4] = u;
            }
        }
    }
}

// pad rows of d_seq: (l >= nn[b]) -> PAD + seg
__global__ __launch_bounds__(256)
void dseq_pad_kernel(const float* __restrict__ seg, const int* __restrict__ nn,
                     float4* __restrict__ out) {
    int idx = blockIdx.x * 256 + threadIdx.x;
    if (idx >= LL * BB * 94) return;
    int k4 = idx % 94;
    int rowi = idx / 94;
    int b = rowi & (BB - 1);
    int l = rowi >> 11;
    if (l < nn[b]) return;
    float4 s4 = ((const float4*)seg)[k4];
    float4 o; o.x = PADV + s4.x; o.y = PADV + s4.y; o.z = PADV + s4.z; o.w = PADV + s4.w;
    out[idx] = o;
}

// ---------------------------------------------------------------------------
// pad-row mu/zlv + exact pad kl contribution (fp32)
// ---------------------------------------------------------------------------
__global__ __launch_bounds__(384)
void pad_vec_kernel(const float* __restrict__ seg,
                    const float* __restrict__ mW1, const float* __restrict__ mb1,
                    const float* __restrict__ mW2, const float* __restrict__ mb2,
                    const float* __restrict__ vW1, const float* __restrict__ vb1,
                    const float* __restrict__ vW2, const float* __restrict__ vb2,
                    float* __restrict__ mu_pad, float* __restrict__ zlv_pad,
                    double* kl_acc, int n_pad_rows) {
    __shared__ float t1[HH], t2[HH], red[HH];
    int j = threadIdx.x;
    if (j < HH) {
        float s1 = mb1[j], s2 = vb1[j];
        for (int k = 0; k < HH; ++k) {
            float p = PADV + seg[k];
            s1 += p * mW1[k * HH + j];
            s2 += p * vW1[k * HH + j];
        }
        t1[j] = fmaxf(s1, 0.0f);
        t2[j] = fmaxf(s2, 0.0f);
    }
    __syncthreads();
    if (j < HH) {
        float m = mb2[j], v = vb2[j];
        for (int k = 0; k < HH; ++k) {
            m += t1[k] * mW2[k * HH + j];
            v += t2[k] * vW2[k * HH + j];
        }
        float z = -fabsf(v);
        mu_pad[j]  = m;
        zlv_pad[j] = z;
        red[j] = 1.0f + z - m * m - expf(z);
    }
    __syncthreads();
    if (j == 0) {
        double s = 0.0;
        for (int k = 0; k < HH; ++k) s += (double)red[k];
        atomicAdd(kl_acc, s * (double)n_pad_rows);
    }
}

__global__ __launch_bounds__(256)
void mask_kernel(const int* __restrict__ nn, float* __restrict__ out) {
    int idx = blockIdx.x * 256 + threadIdx.x;
    if (idx >= BB * LL) return;
    int b = idx / LL, l = idx % LL;
    out[idx] = (l >= nn[b]) ? 1.0f : 0.0f;
}

// fused amvo + kl(real rows); mu/zlv are bf16 compact [N][376]
__global__ __launch_bounds__(256)
void amvo_kl4_kernel(const u16x4* __restrict__ mu, const u16x4* __restrict__ zlv,
                     const float* __restrict__ mu_pad, const float* __restrict__ zlv_pad,
                     const float* __restrict__ con_emb, const float* __restrict__ aff,
                     const float4* __restrict__ eps4,
                     const int* __restrict__ nn, const int* __restrict__ goff,
                     float4* __restrict__ out, float* __restrict__ kl_part) {
    const int T4 = LL * BB * 94;
    float kls = 0.0f;
    for (int idx = blockIdx.x * 256 + threadIdx.x; idx < T4; idx += 2048 * 256) {
        int k4 = idx % 94;
        int rowi = idx / 94;
        int b = rowi & (BB - 1);
        int l = rowi >> 11;
        float4 m, z;
        if (l < nn[b]) {
            size_t o = (size_t)(goff[b] + l) * 94 + k4;
            u16x4 mm = mu[o], zz = zlv[o];
            m.x = bf2f(mm.x); m.y = bf2f(mm.y); m.z = bf2f(mm.z); m.w = bf2f(mm.w);
            z.x = bf2f(zz.x); z.y = bf2f(zz.y); z.z = bf2f(zz.z); z.w = bf2f(zz.w);
            kls += (1.0f + z.x - m.x * m.x - __expf(z.x))
                 + (1.0f + z.y - m.y * m.y - __expf(z.y))
                 + (1.0f + z.z - m.z * m.z - __expf(z.z))
                 + (1.0f + z.w - m.w * m.w - __expf(z.w));
        } else {
            m = ((const float4*)mu_pad)[k4];
            z = ((const float4*)zlv_pad)[k4];
        }
        float4 e = eps4[idx];
        float4 c = ((const float4*)con_emb)[(size_t)b * 94 + k4];
        float af = aff[b];
        float4 o;
        o.x = m.x + __expf(0.5f * z.x) * e.x + c.x + af;
        o.y = m.y + __expf(0.5f * z.y) * e.y + c.y + af;
        o.z = m.z + __expf(0.5f * z.z) * e.z + c.z + af;
        o.w = m.w + __expf(0.5f * z.w) * e.w + c.w + af;
        out[idx] = o;
    }
    __shared__ float red[256];
    red[threadIdx.x] = kls;
    __syncthreads();
    for (int s = 128; s > 0; s >>= 1) {
        if (threadIdx.x < s) red[threadIdx.x] += red[threadIdx.x + s];
        __syncthreads();
    }
    if (threadIdx.x == 0) kl_part[blockIdx.x] = red[0];
}

__global__ __launch_bounds__(256)
void kl_final_kernel(const float* __restrict__ kl_part, int nparts,
                     const double* __restrict__ kl_acc, float* __restrict__ out) {
    __shared__ double red[256];
    double s = 0.0;
    for (int i = threadIdx.x; i < nparts; i += 256) s += (double)kl_part[i];
    red[threadIdx.x] = s;
    __syncthreads();
    for (int st = 128; st > 0; st >>= 1) {
        if (threadIdx.x < st) red[threadIdx.x] += red[threadIdx.x + st];
        __syncthreads();
    }
    if (threadIdx.x == 0) out[0] = (float)(-0.5 * (red[0] + *kl_acc) / 64.0);
}

// global max pool from compact bf16 h3 -> bf16 [BB][384]
__global__ __launch_bounds__(384)
void pool_kernel(const u16* __restrict__ h3b, const int* __restrict__ goff,
                 const int* __restrict__ nn, u16* __restrict__ x2b) {
    int b = blockIdx.x;
    int f = threadIdx.x;
    float m = 0.0f;
    if (f < HH) {
        int off = goff[b], sz = nn[b];
        m = bf2f(h3b[(size_t)off * HH + f]);
        for (int l = 1; l < sz; ++l)
            m = fmaxf(m, bf2f(h3b[(size_t)(off + l) * HH + f]));
    }
    x2b[(size_t)b * 384 + f] = f2bf(m);
}

// ---------------------------------------------------------------------------
extern "C" void kernel_launch(void* const* d_in, const int* in_sizes, int n_in,
                              void* d_out, int out_size, void* d_ws, size_t ws_size,
                              hipStream_t stream) {
    const float* x      = (const float*)d_in[0];
    const float* con    = (const float*)d_in[1];
    const float* aff    = (const float*)d_in[2];
    const float* eps    = (const float*)d_in[3];
    const int*   eidx   = (const int*)  d_in[4];
    const int*   batch  = (const int*)  d_in[5];
    const int*   nn     = (const int*)  d_in[6];
    const int*   pos    = (const int*)  d_in[7];
    const float* seg    = (const float*)d_in[8];
    const float* W1     = (const float*)d_in[9];
    const float* b1     = (const float*)d_in[10];
    const float* W2     = (const float*)d_in[11];
    const float* b2     = (const float*)d_in[12];
    const float* W3     = (const float*)d_in[13];
    const float* b3     = (const float*)d_in[14];
    const float* condW  = (const float*)d_in[15];
    const float* condB  = (const float*)d_in[16];
    const float* mW1    = (const float*)d_in[17];
    const float* mb1    = (const float*)d_in[18];
    const float* mW2    = (const float*)d_in[19];
    const float* mb2    = (const float*)d_in[20];
    const float* vW1    = (const float*)d_in[21];
    const float* vb1    = (const float*)d_in[22];
    const float* vW2    = (const float*)d_in[23];
    const float* vb2    = (const float*)d_in[24];
    const float* fc1W   = (const float*)d_in[25];
    const float* fc1b   = (const float*)d_in[26];
    const float* fc2W   = (const float*)d_in[27];
    const float* fc2b   = (const float*)d_in[28];

    const int N = in_sizes[0] / DF_;          // 81725
    const int E = in_sizes[4] / 2;            // 326900
    const int* erow = eidx;
    const int* ecol = eidx + E;
    const int n_pad_rows = LL * BB - N;

    const size_t dseqN = (size_t)LL * BB * HH;
    float* out_dseq = (float*)d_out;
    float* out_amvo = out_dseq + dseqN;
    float* out_mask = out_amvo + dseqN;
    float* out_pmvo = out_mask + (size_t)BB * LL;
    float* out_kl   = out_pmvo + (size_t)BB * FIN;

    // ---- workspace carve ----
    char* p = (char*)d_ws;
    size_t off = 0;
    auto alloc = [&](size_t bytes) -> char* {
        char* q = p + off;
        off = (off + bytes + 255) & ~(size_t)255;
        return q;
    };
    float*  dinv    = (float*) alloc((size_t)N * 4);
    int*    deg     = (int*)   alloc((size_t)N * 4);
    int*    rowptr  = (int*)   alloc((size_t)(N + 1) * 4);
    int*    cursor  = (int*)   alloc((size_t)N * 4);
    int*    csr_src = (int*)   alloc((size_t)E * 4);
    int*    bsum    = (int*)   alloc((size_t)128 * 4);
    int*    goff    = (int*)   alloc((size_t)(BB + 1) * 4);
    float*  mu_pad  = (float*) alloc(HH * 4);
    float*  zlv_pad = (float*) alloc(HH * 4);
    double* kl_acc  = (double*)alloc(8);
    float*  kl_part = (float*) alloc(2048 * 4);
    float*  b1p     = (float*) alloc(192 * 4);
    float*  b2p     = (float*) alloc(288 * 4);
    float*  b3p     = (float*) alloc(384 * 4);
    float*  segp    = (float*) alloc(384 * 4);
    float*  b768p   = (float*) alloc(768 * 4);
    float*  con_emb = (float*) alloc((size_t)BB * HH * 4);
    u16*    x2b     = (u16*)   alloc((size_t)BB * 384 * 2);
    u16*    tfcb    = (u16*)   alloc((size_t)BB * 1024 * 2);
    u16*    W1T     = (u16*)   alloc((size_t)192 * 96 * 2);
    u16*    W2T     = (u16*)   alloc((size_t)288 * 192 * 2);
    u16*    W3T     = (u16*)   alloc((size_t)384 * 288 * 2);
    u16*    mv1T    = (u16*)   alloc((size_t)768 * 384 * 2);   // [mW1T;vW1T]
    u16*    mW2T    = (u16*)   alloc((size_t)384 * 384 * 2);
    u16*    vW2T    = (u16*)   alloc((size_t)384 * 384 * 2);
    u16*    condWT  = (u16*)   alloc((size_t)384 * 10272 * 2);
    u16*    fc1WT   = (u16*)   alloc((size_t)1024 * 384 * 2);
    u16*    fc2WT   = (u16*)   alloc((size_t)256 * 1024 * 2);
    u16*    a0b     = (u16*)   alloc((size_t)N * 384 * 2);     // bf16(h3+seg) padded
    u16*    h3b     = (u16*)   alloc((size_t)N * 376 * 2);     // bf16 h3 compact
    u16*    mu_b    = (u16*)   alloc((size_t)N * 376 * 2);
    u16*    zlv_b   = (u16*)   alloc((size_t)N * 376 * 2);
    u16*    actb    = (u16*)   alloc((size_t)N * 288 * 2);
    float*  hw      = (float*) alloc((size_t)N * 384 * 4);     // GEMM f32 out

    // bf16 scratch in the (not-yet-written) amvo output region (197 MB)
    char* q = (char*)out_amvo;
    size_t qoff = 0;
    auto qalloc = [&](size_t bytes) -> char* {
        char* r = q + qoff;
        qoff = (qoff + bytes + 255) & ~(size_t)255;
        return r;
    };
    u16* conb = (u16*)qalloc((size_t)BB * 10272 * 2);   // 42 MB
    u16* xb   = (u16*)qalloc((size_t)N * 96 * 2);       // 15.7 MB
    u16* t1b  = (u16*)qalloc((size_t)N * 768 * 2);      // 125.6 MB  (total 183 MB < 197 MB)
    (void)ws_size; (void)n_in; (void)out_size;

    // ---- degree / dinv / CSR / goff ----
    const int NB = cdiv(N, 1024);
    zero_int_kernel<<<cdiv(N, 256), 256, 0, stream>>>(deg, N);
    count_deg_kernel<<<cdiv(E, 256), 256, 0, stream>>>(ecol, deg, E);
    dinv_kernel<<<cdiv(N, 256), 256, 0, stream>>>(deg, dinv, N);
    scan1_kernel<<<NB, 1024, 0, stream>>>(deg, N, rowptr, bsum);
    scan2_kernel<<<1, 64, 0, stream>>>(bsum, NB, rowptr, N);
    scan3_kernel<<<NB, 1024, 0, stream>>>(rowptr, cursor, bsum, N);
    fill_csr_kernel<<<cdiv(E, 256), 256, 0, stream>>>(erow, ecol, cursor, csr_src, E);
    goff_kernel<<<1, 1024, 0, stream>>>(nn, goff, kl_acc);

    // ---- padded bias / seg vectors ----
    pad_f32_kernel<<<1, 256, 0, stream>>>(b1, b1p, 188, 192);
    pad_f32_kernel<<<2, 256, 0, stream>>>(b2, b2p, 282, 288);
    pad_f32_kernel<<<2, 256, 0, stream>>>(b3, b3p, 376, 384);
    pad_f32_kernel<<<2, 256, 0, stream>>>(seg, segp, 376, 384);
    pad_f32_kernel<<<2, 256, 0, stream>>>(mb1, b768p, 376, 384);
    pad_f32_kernel<<<2, 256, 0, stream>>>(vb1, b768p + 384, 376, 384);

    // ---- weight transposes + input casts ----
    auto tc = [&](const float* W, u16* out, int K, int Nn, int Kpad, int Npad) {
        dim3 g(cdiv(Kpad, 32), cdiv(Npad, 32));
        transpose_cast_kernel<<<g, 256, 0, stream>>>(W, out, K, Nn, Kpad, Npad);
    };
    tc(W1,    W1T,    94,    188,  96,    192);
    tc(W2,    W2T,    188,   282,  192,   288);
    tc(W3,    W3T,    282,   376,  288,   384);
    tc(mW1,   mv1T,             376, 376, 384, 384);
    tc(vW1,   mv1T + 384 * 384, 376, 376, 384, 384);
    tc(mW2,   mW2T,   376,   376,  384,   384);
    tc(vW2,   vW2T,   376,   376,  384,   384);
    tc(condW, condWT, 10272, 376,  10272, 384);
    tc(fc1W,  fc1WT,  376,   1024, 384,   1024);
    tc(fc2W,  fc2WT,  1024,  256,  1024,  256);

    cast_pad_kernel<<<(int)(((size_t)N * 96 + 255) / 256), 256, 0, stream>>>(x, xb, N, 94, 96);
    cast4_kernel<<<cdiv(BB * 10272 / 4, 256), 256, 0, stream>>>(
        (const float4*)con, (u16x4*)conb, BB * 10272 / 4);

    // ---- GCN layer 1: 94 -> 188 ----
    mgemm<4>(stream, xb, W1T, nullptr, hw, N, 188, 96, 96, 96, 192, 192, 1);
    gcn_agg_kernel<48, false><<<cdiv(N, 4), 256, 0, stream>>>(
        hw, rowptr, csr_src, dinv, b1p, actb, nullptr, nullptr, nullptr,
        nullptr, nullptr, nullptr, N);

    // ---- GCN layer 2: 188 -> 282 ----
    mgemm<4>(stream, actb, W2T, nullptr, hw, N, 282, 192, 192, 192, 288, 288, 1);
    gcn_agg_kernel<72, false><<<cdiv(N, 4), 256, 0, stream>>>(
        hw, rowptr, csr_src, dinv, b2p, actb, nullptr, nullptr, nullptr,
        nullptr, nullptr, nullptr, N);

    // ---- GCN layer 3: 282 -> 376 (fused dseq scatter + h3b + a0b) ----
    mgemm<4>(stream, actb, W3T, nullptr, hw, N, 376, 288, 288, 288, 384, 384, 1);
    gcn_agg_kernel<96, true><<<cdiv(N, 4), 256, 0, stream>>>(
        hw, rowptr, csr_src, dinv, b3p, nullptr, segp, h3b, a0b,
        batch, pos, (float4*)out_dseq, N);

    // ---- dseq pad rows / mask / pool ----
    dseq_pad_kernel<<<cdiv(LL * BB * 94, 256), 256, 0, stream>>>(seg, nn, (float4*)out_dseq);
    mask_kernel<<<cdiv(BB * LL, 256), 256, 0, stream>>>(nn, out_mask);
    pool_kernel<<<BB, 384, 0, stream>>>(h3b, goff, nn, x2b);

    // ---- mu / logvar (real rows only); stage-1 combined 768-col GEMM ----
    mgemm<2>(stream, a0b, mv1T, b768p, t1b, N, 768, 384, 384, 384, 768, 768, 1);
    mgemm<5>(stream, t1b,       mW2T, mb2, mu_b,  N, 376, 384, 768, 384, 376, 384, 1);
    mgemm<6>(stream, t1b + 384, vW2T, vb2, zlv_b, N, 376, 384, 768, 384, 376, 384, 1);

    pad_vec_kernel<<<1, 384, 0, stream>>>(seg, mW1, mb1, mW2, mb2, vW1, vb1, vW2, vb2,
                                          mu_pad, zlv_pad, kl_acc, n_pad_rows);

    // ---- conditioning embedding ----
    init_bias_kernel<<<cdiv(BB * HH, 256), 256, 0, stream>>>(con_emb, condB, (size_t)BB * HH, HH);
    mgemm<3>(stream, conb, condWT, nullptr, con_emb, BB, 376, 10272, 10272, 10272, 376, 384, 16);

    // ---- amvo + kl ----
    amvo_kl4_kernel<<<2048, 256, 0, stream>>>((const u16x4*)mu_b, (const u16x4*)zlv_b,
                                              mu_pad, zlv_pad, con_emb, aff,
                                              (const float4*)eps, nn, goff,
                                              (float4*)out_amvo, kl_part);
    kl_final_kernel<<<1, 256, 0, stream>>>(kl_part, 2048, kl_acc, out_kl);

    // ---- pmvo head ----
    mgemm<2>(stream, x2b, fc1WT, fc1b, tfcb, BB, 1024, 384, 384, 384, 1024, 1024, 1);
    init_bias_kernel<<<cdiv(BB * FIN, 256), 256, 0, stream>>>(out_pmvo, fc2b, (size_t)BB * FIN, FIN);
    mgemm<3>(stream, tfcb, fc2WT, nullptr, out_pmvo, BB, 256, 1024, 1024, 1024, 256, 256, 8);
}